// Round 4
// baseline (416.893 us; speedup 1.0000x reference)
//
#include <hip/hip_runtime.h>

typedef unsigned short u16;
typedef __attribute__((ext_vector_type(8))) short bf16x8;
typedef __attribute__((ext_vector_type(4))) short bf16x4;
typedef __attribute__((ext_vector_type(4))) float f32x4;
typedef __attribute__((ext_vector_type(4))) unsigned short u16x4;

// Problem constants (fixed by the reference)
#define SEQ 1024
#define BSZ 8
#define NHD 16
#define DHD 64
#define DMODEL 1024

__device__ __forceinline__ u16 f2bf(float x) {
  unsigned u = __float_as_uint(x);
  return (u16)((u + 0x7fffu + ((u >> 16) & 1u)) >> 16);  // RNE
}
__device__ __forceinline__ float bf2f(u16 h) {
  return __uint_as_float(((unsigned)h) << 16);
}

typedef const __attribute__((address_space(1))) unsigned int gu32_t;
typedef __attribute__((address_space(3))) unsigned int lu32_t;
__device__ __forceinline__ void gload16(const void* g, void* l) {
  __builtin_amdgcn_global_load_lds((gu32_t*)g, (lu32_t*)l, 16, 0, 0);
}

// ---------------- cast / transpose kernels ----------------
__global__ void cast_w_k(const float* __restrict__ in, u16* __restrict__ out) {
  size_t i = ((size_t)blockIdx.x * 256 + threadIdx.x) * 4;
  float4 v = *(const float4*)(in + i);
  u16x4 o;
  o[0] = f2bf(v.x); o[1] = f2bf(v.y); o[2] = f2bf(v.z); o[3] = f2bf(v.w);
  *(u16x4*)(out + i) = o;
}

// in [R][C] f32 -> out [C][R] bf16
__global__ void transpose_cast_k(const float* __restrict__ in, u16* __restrict__ out,
                                 int R, int C) {
  __shared__ float tile[32][33];
  int tx = threadIdx.x & 31, ty = threadIdx.x >> 5;
  int bx = blockIdx.x * 32, by = blockIdx.y * 32;
#pragma unroll
  for (int rr = ty; rr < 32; rr += 8)
    tile[rr][tx] = in[(size_t)(by + rr) * C + bx + tx];
  __syncthreads();
#pragma unroll
  for (int rr = ty; rr < 32; rr += 8)
    out[(size_t)(bx + rr) * R + by + tx] = f2bf(tile[tx][rr]);
}

// r_emb [j][n][d] f32 -> [n][j][d] bf16
__global__ void cast_remb_k(const float* __restrict__ in, u16* __restrict__ out) {
  int t = blockIdx.x * 256 + threadIdx.x;  // (j*16+n)*8 + db
  int jn = t >> 3, db = t & 7;
  int j = jn >> 4, n = jn & 15;
  const float* src = in + (size_t)jn * 64 + db * 8;
  u16* dst = out + ((size_t)(n * 1024 + j)) * 64 + db * 8;
#pragma unroll
  for (int e = 0; e < 8; ++e) dst[e] = f2bf(src[e]);
}

// ---------------- GEMM: C[M,N] = A[M,K] @ Bt[N,K]^T  (bf16, 128x128 tile) ----------------
// EPI 0: scatter into q[b][h][i][d], k[b][h][j][d], v TRANSPOSED [b][h][d][j] (bf16).
// EPI 1: yout = resid + C (f32).
template <int EPI>
__global__ __launch_bounds__(256) void gemm_bt(
    const u16* __restrict__ A, const u16* __restrict__ Bt, int K,
    u16* __restrict__ q_o, u16* __restrict__ k_o, u16* __restrict__ v_o,
    const float* __restrict__ resid, float* __restrict__ yout) {
  __shared__ __attribute__((aligned(16))) u16 ldsA[2][4096];  // [128 rows][32 k]
  __shared__ __attribute__((aligned(16))) u16 ldsB[2][4096];
  const int tid = threadIdx.x;
  const int wid = tid >> 6, l = tid & 63;
  const int l15 = l & 15, lg = l >> 4;
  const int bm = blockIdx.y, bn = blockIdx.x;
  const int wm = wid & 1, wn = wid >> 1;
  const size_t ldb = (size_t)K * 2;  // row bytes

  const char* aA = (const char*)A + (size_t)(bm * 128 + wid * 32 + (l >> 2)) * ldb + (l & 3) * 16;
  const char* aB = (const char*)Bt + (size_t)(bn * 128 + wid * 32 + (l >> 2)) * ldb + (l & 3) * 16;

  auto stage = [&](int buf, int kt) {
    const char* sa = aA + (size_t)kt * 64;
    const char* sb = aB + (size_t)kt * 64;
    char* la = (char*)&ldsA[buf][wid * 1024];
    char* lb = (char*)&ldsB[buf][wid * 1024];
    gload16(sa, la);
    gload16(sa + 16 * ldb, la + 1024);
    gload16(sb, lb);
    gload16(sb + 16 * ldb, lb + 1024);
  };

  f32x4 acc[4][4] = {};
  stage(0, 0);
  __syncthreads();
  const int NT = K >> 5;
  for (int t = 0; t < NT; ++t) {
    int cur = t & 1;
    if (t + 1 < NT) stage(cur ^ 1, t + 1);
    bf16x8 af[4], bfr[4];
#pragma unroll
    for (int mi = 0; mi < 4; ++mi)
      af[mi] = *(const bf16x8*)&ldsA[cur][(wm * 64 + mi * 16 + l15) * 32 + lg * 8];
#pragma unroll
    for (int ni = 0; ni < 4; ++ni)
      bfr[ni] = *(const bf16x8*)&ldsB[cur][(wn * 64 + ni * 16 + l15) * 32 + lg * 8];
#pragma unroll
    for (int mi = 0; mi < 4; ++mi)
#pragma unroll
      for (int ni = 0; ni < 4; ++ni)
        acc[mi][ni] = __builtin_amdgcn_mfma_f32_16x16x32_bf16(af[mi], bfr[ni], acc[mi][ni], 0, 0, 0);
    __syncthreads();
  }

  if (EPI == 0) {
#pragma unroll
    for (int mi = 0; mi < 4; ++mi)
#pragma unroll
      for (int ni = 0; ni < 4; ++ni) {
        int c = bn * 128 + wn * 64 + ni * 16 + l15;
        int which = c >> 10, rem = c & 1023, h = rem >> 6, d = rem & 63;
        u16* dst = which == 0 ? q_o : (which == 1 ? k_o : v_o);
#pragma unroll
        for (int r = 0; r < 4; ++r) {
          int rg = bm * 128 + wm * 64 + mi * 16 + lg * 4 + r;
          int i = rg >> 3, bb = rg & 7;
          size_t idx = (which == 2)
              ? ((size_t)(bb * 16 + h) * 64 + d) * 1024 + i       // V^T [b][h][d][j]
              : ((size_t)(bb * 16 + h) * 1024 + i) * 64 + d;      // Q,K [b][h][i][d]
          dst[idx] = f2bf(acc[mi][ni][r]);
        }
      }
  } else {
#pragma unroll
    for (int mi = 0; mi < 4; ++mi)
#pragma unroll
      for (int ni = 0; ni < 4; ++ni) {
        int c = bn * 128 + wn * 64 + ni * 16 + l15;
#pragma unroll
        for (int r = 0; r < 4; ++r) {
          int rg = bm * 128 + wm * 64 + mi * 16 + lg * 4 + r;
          size_t off = (size_t)rg * 1024 + c;
          yout[off] = resid[off] + acc[mi][ni][r];
        }
      }
  }
}

// ---------------- fused causal rel-attention (flash style, barrier-free) ----------------
// Block: 64 q-rows (4 waves x 16 rows), KV tiles of 64, longest blocks first.
// score = 0.125*( (K.(q+rwb))^T + q_i.r_emb[j-i+1023] + r_bias[j-i+1023] )
// K and V^T are L2-resident (256 KB per (b,n), shared by 16 q-blocks) -> MFMA
// fragments are loaded DIRECTLY from global (no LDS staging, no double-buffer,
// NO per-tile barrier). Elds is per-wave; rb is read-only after one barrier.
// V-frags double-pipelined per-dd group (named regs); K loads issue before the
// E-phase MFMAs so their latency hides under E.
__global__ __launch_bounds__(256, 5) void attn_k(
    const u16* __restrict__ qg, const u16* __restrict__ kb, const u16* __restrict__ vtb,
    const u16* __restrict__ remb, const float* __restrict__ rbias,
    const float* __restrict__ rwb, u16* __restrict__ av) {
  __shared__ u16 Elds[4][16][82];   // bf16 E+rb, per-wave, stride 82 (bank spread)
  __shared__ float rb[1088];

  const int tid = threadIdx.x;
  const int wid = tid >> 6, l = tid & 63;
  const int l15 = l & 15, lg = l >> 4;
  const int id = blockIdx.x;
  const int qblk = 15 - (id >> 7);   // longest-first dispatch
  const int bn = id & 127;
  const int b = bn >> 4, n = bn & 15;
  const int ib = qblk * 64;
  const int iw = ib + wid * 16;

  for (int idx = tid; idx < 1088; idx += 256)
    rb[idx] = (idx < 1024) ? rbias[idx * 16 + n] : 0.f;

  // Q fragments: plain (for E) and +r_w_bias (for content score)
  const u16* qrow = qg + ((size_t)bn * 1024 + iw + l15) * 64;
  const float* wbp = rwb + n * 64;
  bf16x8 qf0 = *(const bf16x8*)(qrow + lg * 8);       // B-frag: col i=l15, k=d
  bf16x8 qf1 = *(const bf16x8*)(qrow + 32 + lg * 8);
  bf16x8 qw0, qw1;
#pragma unroll
  for (int e = 0; e < 8; ++e) {
    qw0[e] = (short)f2bf(bf2f((u16)qf0[e]) + wbp[lg * 8 + e]);
    qw1[e] = (short)f2bf(bf2f((u16)qf1[e]) + wbp[32 + lg * 8 + e]);
  }

  f32x4 oacc[4] = {};
  float m_run = -1e30f, l_run = 0.f;

  const size_t kvbase = (size_t)bn * (1024 * 64);
  const int njt = qblk + 1;

  // per-lane fragment base pointers
  const u16* kfp = kb + kvbase + (size_t)l15 * 64 + lg * 8;      // + jb*64 + jj*1024 (+32)
  const u16* vfp = vtb + kvbase + (size_t)l15 * 1024 + lg * 4;   // + dd*16384 + jb + jj*16
  const u16* rembp = remb + (size_t)n * 1024 * 64;

  __syncthreads();  // rb visible (the only barrier)

  for (int jt = 0; jt < njt; ++jt) {
    const int jb = jt * 64;

    // ---- K fragment loads (global, L2-hit; latency hides under E phase) ----
    const u16* kt = kfp + (size_t)jb * 64;
    bf16x8 kf00 = *(const bf16x8*)(kt);
    bf16x8 kf01 = *(const bf16x8*)(kt + 32);
    bf16x8 kf10 = *(const bf16x8*)(kt + 1024);
    bf16x8 kf11 = *(const bf16x8*)(kt + 1056);
    bf16x8 kf20 = *(const bf16x8*)(kt + 2048);
    bf16x8 kf21 = *(const bf16x8*)(kt + 2080);
    bf16x8 kf30 = *(const bf16x8*)(kt + 3072);
    bf16x8 kf31 = *(const bf16x8*)(kt + 3104);

    // ---- E[i,t] = q_i . r_emb[t], t in [tb, tb+80), rb folded, bf16 in LDS ----
    const int tb = jb - iw + 1008;
#pragma unroll
    for (int f = 0; f < 5; ++f) {
      int t = tb + f * 16 + l15;
      int tc = t > 1023 ? 1023 : t;  // >1023 is masked region anyway
      const u16* rr = rembp + (size_t)tc * 64;
      bf16x8 ra0 = *(const bf16x8*)(rr + lg * 8);
      bf16x8 ra1 = *(const bf16x8*)(rr + 32 + lg * 8);
      f32x4 et = {};
      et = __builtin_amdgcn_mfma_f32_16x16x32_bf16(ra0, qf0, et, 0, 0, 0);
      et = __builtin_amdgcn_mfma_f32_16x16x32_bf16(ra1, qf1, et, 0, 0, 0);
#pragma unroll
      for (int r2 = 0; r2 < 4; ++r2) {
        int tw = f * 16 + lg * 4 + r2;
        Elds[wid][l15][tw] = f2bf(et[r2] + rb[tb + tw]);
      }
    }

    // ---- S^T = K.(q+rwb) : acc row j=lg*4+r, col i=l15 ----
    f32x4 st[4];
    __builtin_amdgcn_s_setprio(1);
    {
      f32x4 a;
      a = __builtin_amdgcn_mfma_f32_16x16x32_bf16(kf00, qw0, (f32x4){}, 0, 0, 0);
      st[0] = __builtin_amdgcn_mfma_f32_16x16x32_bf16(kf01, qw1, a, 0, 0, 0);
      a = __builtin_amdgcn_mfma_f32_16x16x32_bf16(kf10, qw0, (f32x4){}, 0, 0, 0);
      st[1] = __builtin_amdgcn_mfma_f32_16x16x32_bf16(kf11, qw1, a, 0, 0, 0);
      a = __builtin_amdgcn_mfma_f32_16x16x32_bf16(kf20, qw0, (f32x4){}, 0, 0, 0);
      st[2] = __builtin_amdgcn_mfma_f32_16x16x32_bf16(kf21, qw1, a, 0, 0, 0);
      a = __builtin_amdgcn_mfma_f32_16x16x32_bf16(kf30, qw0, (f32x4){}, 0, 0, 0);
      st[3] = __builtin_amdgcn_mfma_f32_16x16x32_bf16(kf31, qw1, a, 0, 0, 0);
    }
    __builtin_amdgcn_s_setprio(0);

    // ---- V-frag group for dd=0 (latency hides under softmax VALU) ----
    const u16* vt0 = vfp + jb;
    bf16x4 va0 = *(const bf16x4*)(vt0);
    bf16x4 va1 = *(const bf16x4*)(vt0 + 16);
    bf16x4 va2 = *(const bf16x4*)(vt0 + 32);
    bf16x4 va3 = *(const bf16x4*)(vt0 + 48);

    // ---- softmax (scores in-place in st) ----
    const bool domask = (jb == ib);  // only the diagonal tile needs masking
    float tmax = -1e30f;
#pragma unroll
    for (int jj = 0; jj < 4; ++jj)
#pragma unroll
      for (int r2 = 0; r2 < 4; ++r2) {
        int jl = jj * 16 + lg * 4 + r2;
        float v = st[jj][r2] + bf2f(Elds[wid][l15][jl - l15 + 15]);
        v *= 0.125f;
        if (domask && (jl > wid * 16 + l15)) v = -1e30f;
        st[jj][r2] = v;
        tmax = fmaxf(tmax, v);
      }
    tmax = fmaxf(tmax, __shfl_xor(tmax, 16));
    tmax = fmaxf(tmax, __shfl_xor(tmax, 32));

    // defer-max (T13): only rescale when the running max grew by > 8
    if (!__all(tmax - m_run <= 8.0f)) {
      float m_new = fmaxf(m_run, tmax);
      float fac = __expf(m_run - m_new);
      m_run = m_new;
      l_run *= fac;
      float fo[4];
#pragma unroll
      for (int r2 = 0; r2 < 4; ++r2) fo[r2] = __shfl(fac, (l & 48) | (lg * 4 + r2));
#pragma unroll
      for (int dd = 0; dd < 4; ++dd)
#pragma unroll
        for (int r2 = 0; r2 < 4; ++r2) oacc[dd][r2] *= fo[r2];
    }

    float psum = 0.f;
    bf16x4 pa[4];
#pragma unroll
    for (int jj = 0; jj < 4; ++jj)
#pragma unroll
      for (int r2 = 0; r2 < 4; ++r2) {
        float p = __expf(st[jj][r2] - m_run);
        psum += p;
        pa[jj][r2] = (short)f2bf(p);
      }
    psum += __shfl_xor(psum, 16);
    psum += __shfl_xor(psum, 32);
    l_run += psum;

    // ---- PV: P (S^T-acc layout) is the 16x16x16 A-fragment; V groups pipelined ----
    __builtin_amdgcn_s_setprio(1);
    {
      const u16* vt1 = vfp + 16384 + jb;
      bf16x4 vb0 = *(const bf16x4*)(vt1);
      bf16x4 vb1 = *(const bf16x4*)(vt1 + 16);
      bf16x4 vb2 = *(const bf16x4*)(vt1 + 32);
      bf16x4 vb3 = *(const bf16x4*)(vt1 + 48);
      oacc[0] = __builtin_amdgcn_mfma_f32_16x16x16bf16_1k(pa[0], va0, oacc[0], 0, 0, 0);
      oacc[0] = __builtin_amdgcn_mfma_f32_16x16x16bf16_1k(pa[1], va1, oacc[0], 0, 0, 0);
      oacc[0] = __builtin_amdgcn_mfma_f32_16x16x16bf16_1k(pa[2], va2, oacc[0], 0, 0, 0);
      oacc[0] = __builtin_amdgcn_mfma_f32_16x16x16bf16_1k(pa[3], va3, oacc[0], 0, 0, 0);
      const u16* vt2 = vfp + 32768 + jb;
      va0 = *(const bf16x4*)(vt2);
      va1 = *(const bf16x4*)(vt2 + 16);
      va2 = *(const bf16x4*)(vt2 + 32);
      va3 = *(const bf16x4*)(vt2 + 48);
      oacc[1] = __builtin_amdgcn_mfma_f32_16x16x16bf16_1k(pa[0], vb0, oacc[1], 0, 0, 0);
      oacc[1] = __builtin_amdgcn_mfma_f32_16x16x16bf16_1k(pa[1], vb1, oacc[1], 0, 0, 0);
      oacc[1] = __builtin_amdgcn_mfma_f32_16x16x16bf16_1k(pa[2], vb2, oacc[1], 0, 0, 0);
      oacc[1] = __builtin_amdgcn_mfma_f32_16x16x16bf16_1k(pa[3], vb3, oacc[1], 0, 0, 0);
      const u16* vt3 = vfp + 49152 + jb;
      vb0 = *(const bf16x4*)(vt3);
      vb1 = *(const bf16x4*)(vt3 + 16);
      vb2 = *(const bf16x4*)(vt3 + 32);
      vb3 = *(const bf16x4*)(vt3 + 48);
      oacc[2] = __builtin_amdgcn_mfma_f32_16x16x16bf16_1k(pa[0], va0, oacc[2], 0, 0, 0);
      oacc[2] = __builtin_amdgcn_mfma_f32_16x16x16bf16_1k(pa[1], va1, oacc[2], 0, 0, 0);
      oacc[2] = __builtin_amdgcn_mfma_f32_16x16x16bf16_1k(pa[2], va2, oacc[2], 0, 0, 0);
      oacc[2] = __builtin_amdgcn_mfma_f32_16x16x16bf16_1k(pa[3], va3, oacc[2], 0, 0, 0);
      oacc[3] = __builtin_amdgcn_mfma_f32_16x16x16bf16_1k(pa[0], vb0, oacc[3], 0, 0, 0);
      oacc[3] = __builtin_amdgcn_mfma_f32_16x16x16bf16_1k(pa[1], vb1, oacc[3], 0, 0, 0);
      oacc[3] = __builtin_amdgcn_mfma_f32_16x16x16bf16_1k(pa[2], vb2, oacc[3], 0, 0, 0);
      oacc[3] = __builtin_amdgcn_mfma_f32_16x16x16bf16_1k(pa[3], vb3, oacc[3], 0, 0, 0);
    }
    __builtin_amdgcn_s_setprio(0);
  }

  float linv = 1.f / l_run;
  float io[4];
#pragma unroll
  for (int r2 = 0; r2 < 4; ++r2) io[r2] = __shfl(linv, (l & 48) | (lg * 4 + r2));
#pragma unroll
  for (int dd = 0; dd < 4; ++dd)
#pragma unroll
    for (int r2 = 0; r2 < 4; ++r2) {
      int ig = iw + lg * 4 + r2;
      av[((size_t)ig * 8 + b) * 1024 + n * 64 + dd * 16 + l15] = f2bf(oacc[dd][r2] * io[r2]);
    }
}

// ---------------- in-place LayerNorm over rows of 1024 ----------------
__global__ void ln_k(float* __restrict__ y, const float* __restrict__ g,
                     const float* __restrict__ be) {
  const int row = blockIdx.x, tid = threadIdx.x;
  float* p = y + (size_t)row * 1024;
  float4 v = ((const float4*)p)[tid];
  float s1 = v.x + v.y + v.z + v.w;
  float s2 = v.x * v.x + v.y * v.y + v.z * v.z + v.w * v.w;
#pragma unroll
  for (int mk = 1; mk < 64; mk <<= 1) {
    s1 += __shfl_xor(s1, mk);
    s2 += __shfl_xor(s2, mk);
  }
  __shared__ float as1[4], as2[4];
  if ((tid & 63) == 0) { as1[tid >> 6] = s1; as2[tid >> 6] = s2; }
  __syncthreads();
  s1 = as1[0] + as1[1] + as1[2] + as1[3];
  s2 = as2[0] + as2[1] + as2[2] + as2[3];
  float mu = s1 * (1.f / 1024.f);
  float var = s2 * (1.f / 1024.f) - mu * mu;
  float rs = rsqrtf(var + 1e-5f);
  float4 gg = ((const float4*)g)[tid];
  float4 bb = ((const float4*)be)[tid];
  float4 o;
  o.x = (v.x - mu) * rs * gg.x + bb.x;
  o.y = (v.y - mu) * rs * gg.y + bb.y;
  o.z = (v.z - mu) * rs * gg.z + bb.z;
  o.w = (v.w - mu) * rs * gg.w + bb.w;
  ((float4*)p)[tid] = o;
}

extern "C" void kernel_launch(void* const* d_in, const int* in_sizes, int n_in,
                              void* d_out, int out_size, void* d_ws, size_t ws_size,
                              hipStream_t stream) {
  (void)in_sizes; (void)n_in; (void)out_size; (void)ws_size;
  const float* w      = (const float*)d_in[0];
  const float* r_emb  = (const float*)d_in[1];
  const float* r_wb   = (const float*)d_in[2];
  const float* r_bias = (const float*)d_in[3];
  const float* qkv_w  = (const float*)d_in[4];
  const float* o_w    = (const float*)d_in[5];
  const float* ln_g   = (const float*)d_in[6];
  const float* ln_b   = (const float*)d_in[7];
  float* out = (float*)d_out;
  char* ws = (char*)d_ws;

  // workspace layout (bytes); total 77,594,624
  u16* w_b    = (u16*)(ws + 0);          // 16 MB; reused as attn_vec after QKV GEMM
  u16* qkvw_t = (u16*)(ws + 16777216);   // 6 MB  [3072][1024]
  u16* ow_t   = (u16*)(ws + 23068672);   // 2 MB  [1024][1024]
  u16* remb_t = (u16*)(ws + 25165824);   // 2 MB  [n][j][d]
  u16* q_b    = (u16*)(ws + 27262976);   // 16 MB [b][h][i][d]
  u16* k_b    = (u16*)(ws + 44040192);   // 16 MB [b][h][j][d]
  u16* vt_b   = (u16*)(ws + 60817408);   // 16 MB [b][h][d][j]  (transposed!)
  u16* av_b   = w_b;

  cast_w_k<<<8192, 256, 0, stream>>>(w, w_b);
  transpose_cast_k<<<dim3(96, 32), 256, 0, stream>>>(qkv_w, qkvw_t, 1024, 3072);
  transpose_cast_k<<<dim3(32, 32), 256, 0, stream>>>(o_w, ow_t, 1024, 1024);
  cast_remb_k<<<512, 256, 0, stream>>>(r_emb, remb_t);
  gemm_bt<0><<<dim3(24, 64), 256, 0, stream>>>(w_b, qkvw_t, 1024, q_b, k_b, vt_b, nullptr, nullptr);
  attn_k<<<dim3(2048), 256, 0, stream>>>(q_b, k_b, vt_b, remb_t, r_bias, r_wb, av_b);
  gemm_bt<1><<<dim3(8, 64), 256, 0, stream>>>(av_b, ow_t, 1024, nullptr, nullptr, nullptr, w, out);
  ln_k<<<8192, 256, 0, stream>>>(out, ln_g, ln_b);
}

// Round 5
// 247.415 us; speedup vs baseline: 1.6850x; 1.6850x over previous
//
#include <hip/hip_runtime.h>

typedef unsigned short u16;
typedef __attribute__((ext_vector_type(8))) short bf16x8;
typedef __attribute__((ext_vector_type(4))) short bf16x4;
typedef __attribute__((ext_vector_type(4))) float f32x4;
typedef __attribute__((ext_vector_type(4))) unsigned short u16x4;

// Problem constants (fixed by the reference)
#define SEQ 1024
#define BSZ 8
#define NHD 16
#define DHD 64
#define DMODEL 1024

__device__ __forceinline__ u16 f2bf(float x) {
  unsigned u = __float_as_uint(x);
  return (u16)((u + 0x7fffu + ((u >> 16) & 1u)) >> 16);  // RNE
}
__device__ __forceinline__ float bf2f(u16 h) {
  return __uint_as_float(((unsigned)h) << 16);
}

typedef const __attribute__((address_space(1))) unsigned int gu32_t;
typedef __attribute__((address_space(3))) unsigned int lu32_t;
__device__ __forceinline__ void gload16(const void* g, void* l) {
  __builtin_amdgcn_global_load_lds((gu32_t*)g, (lu32_t*)l, 16, 0, 0);
}

// ---------------- cast / transpose kernels ----------------
__global__ void cast_w_k(const float* __restrict__ in, u16* __restrict__ out) {
  size_t i = ((size_t)blockIdx.x * 256 + threadIdx.x) * 4;
  float4 v = *(const float4*)(in + i);
  u16x4 o;
  o[0] = f2bf(v.x); o[1] = f2bf(v.y); o[2] = f2bf(v.z); o[3] = f2bf(v.w);
  *(u16x4*)(out + i) = o;
}

// in [R][C] f32 -> out [C][R] bf16
__global__ void transpose_cast_k(const float* __restrict__ in, u16* __restrict__ out,
                                 int R, int C) {
  __shared__ float tile[32][33];
  int tx = threadIdx.x & 31, ty = threadIdx.x >> 5;
  int bx = blockIdx.x * 32, by = blockIdx.y * 32;
#pragma unroll
  for (int rr = ty; rr < 32; rr += 8)
    tile[rr][tx] = in[(size_t)(by + rr) * C + bx + tx];
  __syncthreads();
#pragma unroll
  for (int rr = ty; rr < 32; rr += 8)
    out[(size_t)(bx + rr) * R + by + tx] = f2bf(tile[tx][rr]);
}

// r_emb [j][n][d] f32 -> MFMA-A-fragment order:
// rf[n][t16][ks][lane][8], lane = (t&15) | ((d>>3)&3)<<4, elems d&7
__global__ void cast_remb_k(const float* __restrict__ in, u16* __restrict__ out) {
  int t0 = blockIdx.x * 256 + threadIdx.x;  // (j*16+n)*8 + db
  int jn = t0 >> 3, db = t0 & 7;            // db: which 8-d octet
  int j = jn >> 4, n = jn & 15;
  const float* src = in + (size_t)jn * 64 + db * 8;
  u16* dst = out + (size_t)n * 65536 + (size_t)(j >> 4) * 1024 + (db >> 2) * 512 +
             (((j & 15) | ((db & 3) << 4)) << 3);
#pragma unroll
  for (int e = 0; e < 8; ++e) dst[e] = f2bf(src[e]);
}

// ---------------- GEMM: C[M,N] = A[M,K] @ Bt[N,K]^T  (bf16, 128x128 tile) ----------------
// EPI 0: scatter q normal [b][h][i][d]; K and V in MFMA-fragment order (see attn_k).
// EPI 1: yout = resid + C (f32).
template <int EPI>
__global__ __launch_bounds__(256) void gemm_bt(
    const u16* __restrict__ A, const u16* __restrict__ Bt, int K,
    u16* __restrict__ q_o, u16* __restrict__ k_o, u16* __restrict__ v_o,
    const float* __restrict__ resid, float* __restrict__ yout) {
  __shared__ __attribute__((aligned(16))) u16 ldsA[2][4096];  // [128 rows][32 k]
  __shared__ __attribute__((aligned(16))) u16 ldsB[2][4096];
  const int tid = threadIdx.x;
  const int wid = tid >> 6, l = tid & 63;
  const int l15 = l & 15, lg = l >> 4;
  const int bm = blockIdx.y, bn = blockIdx.x;
  const int wm = wid & 1, wn = wid >> 1;
  const size_t ldb = (size_t)K * 2;  // row bytes

  const char* aA = (const char*)A + (size_t)(bm * 128 + wid * 32 + (l >> 2)) * ldb + (l & 3) * 16;
  const char* aB = (const char*)Bt + (size_t)(bn * 128 + wid * 32 + (l >> 2)) * ldb + (l & 3) * 16;

  auto stage = [&](int buf, int kt) {
    const char* sa = aA + (size_t)kt * 64;
    const char* sb = aB + (size_t)kt * 64;
    char* la = (char*)&ldsA[buf][wid * 1024];
    char* lb = (char*)&ldsB[buf][wid * 1024];
    gload16(sa, la);
    gload16(sa + 16 * ldb, la + 1024);
    gload16(sb, lb);
    gload16(sb + 16 * ldb, lb + 1024);
  };

  f32x4 acc[4][4] = {};
  stage(0, 0);
  __syncthreads();
  const int NT = K >> 5;
  for (int t = 0; t < NT; ++t) {
    int cur = t & 1;
    if (t + 1 < NT) stage(cur ^ 1, t + 1);
    bf16x8 af[4], bfr[4];
#pragma unroll
    for (int mi = 0; mi < 4; ++mi)
      af[mi] = *(const bf16x8*)&ldsA[cur][(wm * 64 + mi * 16 + l15) * 32 + lg * 8];
#pragma unroll
    for (int ni = 0; ni < 4; ++ni)
      bfr[ni] = *(const bf16x8*)&ldsB[cur][(wn * 64 + ni * 16 + l15) * 32 + lg * 8];
#pragma unroll
    for (int mi = 0; mi < 4; ++mi)
#pragma unroll
      for (int ni = 0; ni < 4; ++ni)
        acc[mi][ni] = __builtin_amdgcn_mfma_f32_16x16x32_bf16(af[mi], bfr[ni], acc[mi][ni], 0, 0, 0);
    __syncthreads();
  }

  if (EPI == 0) {
#pragma unroll
    for (int mi = 0; mi < 4; ++mi)
#pragma unroll
      for (int ni = 0; ni < 4; ++ni) {
        int c = bn * 128 + wn * 64 + ni * 16 + l15;
        int which = c >> 10, rem = c & 1023, h = rem >> 6, d = rem & 63;
        u16* dst = which == 0 ? q_o : (which == 1 ? k_o : v_o);
#pragma unroll
        for (int r = 0; r < 4; ++r) {
          int rg = bm * 128 + wm * 64 + mi * 16 + lg * 4 + r;
          int i = rg >> 3, bb = rg & 7;
          int bn2 = bb * 16 + h;
          size_t idx;
          if (which == 0) {
            idx = ((size_t)bn2 * 1024 + i) * 64 + d;
          } else if (which == 1) {
            // K frag: [bn][j16][ks][lane][8]
            idx = (size_t)bn2 * 65536 + (size_t)(i >> 4) * 1024 + (d >> 5) * 512 +
                  (((i & 15) | (((d >> 3) & 3) << 4)) << 3) + (d & 7);
          } else {
            // V frag: [bn][j16][dd][lane][4]
            idx = (size_t)bn2 * 65536 + (size_t)(i >> 4) * 1024 + (d >> 4) * 256 +
                  (((d & 15) | (((i >> 2) & 3) << 4)) << 2) + (i & 3);
          }
          dst[idx] = f2bf(acc[mi][ni][r]);
        }
      }
  } else {
#pragma unroll
    for (int mi = 0; mi < 4; ++mi)
#pragma unroll
      for (int ni = 0; ni < 4; ++ni) {
        int c = bn * 128 + wn * 64 + ni * 16 + l15;
#pragma unroll
        for (int r = 0; r < 4; ++r) {
          int rg = bm * 128 + wm * 64 + mi * 16 + lg * 4 + r;
          size_t off = (size_t)rg * 1024 + c;
          yout[off] = resid[off] + acc[mi][ni][r];
        }
      }
  }
}

// ---------------- fused causal rel-attention (barrier-free, frag-direct) ----------------
// Block: 64 q-rows (4 waves x 16 rows), KV tiles of 64, longest blocks first.
// score = 0.125*( (K.(q+rwb))^T + q_i.r_emb[j-i+1023] + r_bias[j-i+1023] )
// K, V, r_emb stored in MFMA-fragment order in global: every operand load is a
// fully-coalesced 512B/1KB wave load served by L2. No K/V LDS, no loop barriers.
// Elds (per-wave diag-gather buffer) is f32: b128 writes, aligned f32 reads.
// XCD grouping: id%8 keyed to head%8 -> per-XCD working set ~4.25 MB ~= its L2.
__global__ __launch_bounds__(256, 6) void attn_k(
    const u16* __restrict__ qg, const u16* __restrict__ kf, const u16* __restrict__ vf,
    const u16* __restrict__ rf, const float* __restrict__ rbias,
    const float* __restrict__ rwb, u16* __restrict__ av) {
  __shared__ __attribute__((aligned(16))) float Elds[4][16][84];
  __shared__ __attribute__((aligned(16))) float rb[1088];

  const int tid = threadIdx.x;
  const int wid = tid >> 6, l = tid & 63;
  const int l15 = l & 15, lg = l >> 4;
  const int id = blockIdx.x;
  const int qblk = 15 - (id >> 7);   // longest-first dispatch
  const int n = (id & 7) | (((id >> 3) & 1) << 3);  // id%8 keys head%8 (XCD grouping)
  const int b = (id >> 4) & 7;
  const int bn = b * 16 + n;
  const int ib = qblk * 64;
  const int iw = ib + wid * 16;

  for (int idx = tid; idx < 1088; idx += 256)
    rb[idx] = (idx < 1024) ? rbias[idx * 16 + n] : 0.f;

  // Q fragments: plain (for E) and +r_w_bias (for content score)
  const u16* qrow = qg + ((size_t)bn * 1024 + iw + l15) * 64;
  const float* wbp = rwb + n * 64;
  bf16x8 qf0 = *(const bf16x8*)(qrow + lg * 8);       // B-frag: col i=l15, k=d
  bf16x8 qf1 = *(const bf16x8*)(qrow + 32 + lg * 8);
  bf16x8 qw0, qw1;
#pragma unroll
  for (int e = 0; e < 8; ++e) {
    qw0[e] = (short)f2bf(bf2f((u16)qf0[e]) + wbp[lg * 8 + e]);
    qw1[e] = (short)f2bf(bf2f((u16)qf1[e]) + wbp[32 + lg * 8 + e]);
  }

  f32x4 oacc[4] = {};
  float m_run = -1e30f, l_run = 0.f;

  // per-lane fragment pointers (frag layouts: lane-major, fully coalesced)
  const u16* kfp = kf + (size_t)bn * 65536 + l * 8;
  const u16* vfp = vf + (size_t)bn * 65536 + l * 4;
  const u16* rfp = rf + (size_t)n * 65536 + l * 8;

  __syncthreads();  // rb visible (the only barrier)

  const int njt = qblk + 1;
  for (int jt = 0; jt < njt; ++jt) {
    const int jb = jt * 64;

    // ---- K fragments: 8 coalesced 1KB loads ----
    const u16* kt = kfp + jt * 4096;
    bf16x8 kf00 = *(const bf16x8*)(kt);
    bf16x8 kf01 = *(const bf16x8*)(kt + 512);
    bf16x8 kf10 = *(const bf16x8*)(kt + 1024);
    bf16x8 kf11 = *(const bf16x8*)(kt + 1536);
    bf16x8 kf20 = *(const bf16x8*)(kt + 2048);
    bf16x8 kf21 = *(const bf16x8*)(kt + 2560);
    bf16x8 kf30 = *(const bf16x8*)(kt + 3072);
    bf16x8 kf31 = *(const bf16x8*)(kt + 3584);

    // ---- E[i,t] = q_i . r_emb[t], t in [tb, tb+80), rb folded, f32 in LDS ----
    const int tb = jb - iw + 1008;
    const int tb16 = tb >> 4;
#pragma unroll
    for (int f = 0; f < 5; ++f) {
      int t16 = tb16 + f;
      if (t16 > 63) t16 = 63;  // >1023 rows are masked region anyway
      const u16* rr = rfp + t16 * 1024;
      bf16x8 ra0 = *(const bf16x8*)(rr);
      bf16x8 ra1 = *(const bf16x8*)(rr + 512);
      f32x4 et = {};
      et = __builtin_amdgcn_mfma_f32_16x16x32_bf16(ra0, qf0, et, 0, 0, 0);
      et = __builtin_amdgcn_mfma_f32_16x16x32_bf16(ra1, qf1, et, 0, 0, 0);
      f32x4 rb4 = *(const f32x4*)&rb[tb + f * 16 + lg * 4];
      et = et + rb4;
      *(f32x4*)&Elds[wid][l15][f * 16 + lg * 4] = et;
    }

    // ---- S^T = K.(q+rwb) : acc row j=lg*4+r, col i=l15 ----
    f32x4 st[4];
    __builtin_amdgcn_s_setprio(1);
    {
      f32x4 a;
      a = __builtin_amdgcn_mfma_f32_16x16x32_bf16(kf00, qw0, (f32x4){}, 0, 0, 0);
      st[0] = __builtin_amdgcn_mfma_f32_16x16x32_bf16(kf01, qw1, a, 0, 0, 0);
      a = __builtin_amdgcn_mfma_f32_16x16x32_bf16(kf10, qw0, (f32x4){}, 0, 0, 0);
      st[1] = __builtin_amdgcn_mfma_f32_16x16x32_bf16(kf11, qw1, a, 0, 0, 0);
      a = __builtin_amdgcn_mfma_f32_16x16x32_bf16(kf20, qw0, (f32x4){}, 0, 0, 0);
      st[2] = __builtin_amdgcn_mfma_f32_16x16x32_bf16(kf21, qw1, a, 0, 0, 0);
      a = __builtin_amdgcn_mfma_f32_16x16x32_bf16(kf30, qw0, (f32x4){}, 0, 0, 0);
      st[3] = __builtin_amdgcn_mfma_f32_16x16x32_bf16(kf31, qw1, a, 0, 0, 0);
    }
    __builtin_amdgcn_s_setprio(0);

    // ---- V-frag group for dd=0 (coalesced 512B loads; hide under softmax) ----
    const u16* vt0 = vfp + jt * 4096;
    bf16x4 va0 = *(const bf16x4*)(vt0);
    bf16x4 va1 = *(const bf16x4*)(vt0 + 1024);
    bf16x4 va2 = *(const bf16x4*)(vt0 + 2048);
    bf16x4 va3 = *(const bf16x4*)(vt0 + 3072);

    // ---- softmax (scores in-place in st) ----
    const bool domask = (jb == ib);  // only the diagonal tile needs masking
    float tmax = -1e30f;
#pragma unroll
    for (int jj = 0; jj < 4; ++jj)
#pragma unroll
      for (int r2 = 0; r2 < 4; ++r2) {
        int jl = jj * 16 + lg * 4 + r2;
        float v = st[jj][r2] + Elds[wid][l15][jl - l15 + 15];
        v *= 0.125f;
        if (domask && (jl > wid * 16 + l15)) v = -1e30f;
        st[jj][r2] = v;
        tmax = fmaxf(tmax, v);
      }
    tmax = fmaxf(tmax, __shfl_xor(tmax, 16));
    tmax = fmaxf(tmax, __shfl_xor(tmax, 32));

    // defer-max (T13): only rescale when the running max grew by > 8
    if (!__all(tmax - m_run <= 8.0f)) {
      float m_new = fmaxf(m_run, tmax);
      float fac = __expf(m_run - m_new);
      m_run = m_new;
      l_run *= fac;
      float fo[4];
#pragma unroll
      for (int r2 = 0; r2 < 4; ++r2) fo[r2] = __shfl(fac, (l & 48) | (lg * 4 + r2));
#pragma unroll
      for (int dd = 0; dd < 4; ++dd)
#pragma unroll
        for (int r2 = 0; r2 < 4; ++r2) oacc[dd][r2] *= fo[r2];
    }

    float psum = 0.f;
    bf16x4 pa[4];
#pragma unroll
    for (int jj = 0; jj < 4; ++jj)
#pragma unroll
      for (int r2 = 0; r2 < 4; ++r2) {
        float p = __expf(st[jj][r2] - m_run);
        psum += p;
        pa[jj][r2] = (short)f2bf(p);
      }
    psum += __shfl_xor(psum, 16);
    psum += __shfl_xor(psum, 32);
    l_run += psum;

    // ---- PV: P (S^T-acc layout) is the 16x16x16 A-fragment; V groups pipelined ----
    __builtin_amdgcn_s_setprio(1);
    {
      const u16* vt1 = vt0 + 256;  // dd=1
      bf16x4 vb0 = *(const bf16x4*)(vt1);
      bf16x4 vb1 = *(const bf16x4*)(vt1 + 1024);
      bf16x4 vb2 = *(const bf16x4*)(vt1 + 2048);
      bf16x4 vb3 = *(const bf16x4*)(vt1 + 3072);
      oacc[0] = __builtin_amdgcn_mfma_f32_16x16x16bf16_1k(pa[0], va0, oacc[0], 0, 0, 0);
      oacc[0] = __builtin_amdgcn_mfma_f32_16x16x16bf16_1k(pa[1], va1, oacc[0], 0, 0, 0);
      oacc[0] = __builtin_amdgcn_mfma_f32_16x16x16bf16_1k(pa[2], va2, oacc[0], 0, 0, 0);
      oacc[0] = __builtin_amdgcn_mfma_f32_16x16x16bf16_1k(pa[3], va3, oacc[0], 0, 0, 0);
      const u16* vt2 = vt0 + 512;  // dd=2
      va0 = *(const bf16x4*)(vt2);
      va1 = *(const bf16x4*)(vt2 + 1024);
      va2 = *(const bf16x4*)(vt2 + 2048);
      va3 = *(const bf16x4*)(vt2 + 3072);
      oacc[1] = __builtin_amdgcn_mfma_f32_16x16x16bf16_1k(pa[0], vb0, oacc[1], 0, 0, 0);
      oacc[1] = __builtin_amdgcn_mfma_f32_16x16x16bf16_1k(pa[1], vb1, oacc[1], 0, 0, 0);
      oacc[1] = __builtin_amdgcn_mfma_f32_16x16x16bf16_1k(pa[2], vb2, oacc[1], 0, 0, 0);
      oacc[1] = __builtin_amdgcn_mfma_f32_16x16x16bf16_1k(pa[3], vb3, oacc[1], 0, 0, 0);
      const u16* vt3 = vt0 + 768;  // dd=3
      vb0 = *(const bf16x4*)(vt3);
      vb1 = *(const bf16x4*)(vt3 + 1024);
      vb2 = *(const bf16x4*)(vt3 + 2048);
      vb3 = *(const bf16x4*)(vt3 + 3072);
      oacc[2] = __builtin_amdgcn_mfma_f32_16x16x16bf16_1k(pa[0], va0, oacc[2], 0, 0, 0);
      oacc[2] = __builtin_amdgcn_mfma_f32_16x16x16bf16_1k(pa[1], va1, oacc[2], 0, 0, 0);
      oacc[2] = __builtin_amdgcn_mfma_f32_16x16x16bf16_1k(pa[2], va2, oacc[2], 0, 0, 0);
      oacc[2] = __builtin_amdgcn_mfma_f32_16x16x16bf16_1k(pa[3], va3, oacc[2], 0, 0, 0);
      oacc[3] = __builtin_amdgcn_mfma_f32_16x16x16bf16_1k(pa[0], vb0, oacc[3], 0, 0, 0);
      oacc[3] = __builtin_amdgcn_mfma_f32_16x16x16bf16_1k(pa[1], vb1, oacc[3], 0, 0, 0);
      oacc[3] = __builtin_amdgcn_mfma_f32_16x16x16bf16_1k(pa[2], vb2, oacc[3], 0, 0, 0);
      oacc[3] = __builtin_amdgcn_mfma_f32_16x16x16bf16_1k(pa[3], vb3, oacc[3], 0, 0, 0);
    }
    __builtin_amdgcn_s_setprio(0);
  }

  float linv = 1.f / l_run;
  float io[4];
#pragma unroll
  for (int r2 = 0; r2 < 4; ++r2) io[r2] = __shfl(linv, (l & 48) | (lg * 4 + r2));
#pragma unroll
  for (int dd = 0; dd < 4; ++dd)
#pragma unroll
    for (int r2 = 0; r2 < 4; ++r2) {
      int ig = iw + lg * 4 + r2;
      av[((size_t)ig * 8 + b) * 1024 + n * 64 + dd * 16 + l15] = f2bf(oacc[dd][r2] * io[r2]);
    }
}

// ---------------- in-place LayerNorm over rows of 1024 ----------------
__global__ void ln_k(float* __restrict__ y, const float* __restrict__ g,
                     const float* __restrict__ be) {
  const int row = blockIdx.x, tid = threadIdx.x;
  float* p = y + (size_t)row * 1024;
  float4 v = ((const float4*)p)[tid];
  float s1 = v.x + v.y + v.z + v.w;
  float s2 = v.x * v.x + v.y * v.y + v.z * v.z + v.w * v.w;
#pragma unroll
  for (int mk = 1; mk < 64; mk <<= 1) {
    s1 += __shfl_xor(s1, mk);
    s2 += __shfl_xor(s2, mk);
  }
  __shared__ float as1[4], as2[4];
  if ((tid & 63) == 0) { as1[tid >> 6] = s1; as2[tid >> 6] = s2; }
  __syncthreads();
  s1 = as1[0] + as1[1] + as1[2] + as1[3];
  s2 = as2[0] + as2[1] + as2[2] + as2[3];
  float mu = s1 * (1.f / 1024.f);
  float var = s2 * (1.f / 1024.f) - mu * mu;
  float rs = rsqrtf(var + 1e-5f);
  float4 gg = ((const float4*)g)[tid];
  float4 bb = ((const float4*)be)[tid];
  float4 o;
  o.x = (v.x - mu) * rs * gg.x + bb.x;
  o.y = (v.y - mu) * rs * gg.y + bb.y;
  o.z = (v.z - mu) * rs * gg.z + bb.z;
  o.w = (v.w - mu) * rs * gg.w + bb.w;
  ((float4*)p)[tid] = o;
}

extern "C" void kernel_launch(void* const* d_in, const int* in_sizes, int n_in,
                              void* d_out, int out_size, void* d_ws, size_t ws_size,
                              hipStream_t stream) {
  (void)in_sizes; (void)n_in; (void)out_size; (void)ws_size;
  const float* w      = (const float*)d_in[0];
  const float* r_emb  = (const float*)d_in[1];
  const float* r_wb   = (const float*)d_in[2];
  const float* r_bias = (const float*)d_in[3];
  const float* qkv_w  = (const float*)d_in[4];
  const float* o_w    = (const float*)d_in[5];
  const float* ln_g   = (const float*)d_in[6];
  const float* ln_b   = (const float*)d_in[7];
  float* out = (float*)d_out;
  char* ws = (char*)d_ws;

  // workspace layout (bytes); total 77,594,624
  u16* w_b    = (u16*)(ws + 0);          // 16 MB; reused as attn_vec after QKV GEMM
  u16* qkvw_t = (u16*)(ws + 16777216);   // 6 MB  [3072][1024]
  u16* ow_t   = (u16*)(ws + 23068672);   // 2 MB  [1024][1024]
  u16* remb_f = (u16*)(ws + 25165824);   // 2 MB  frag order [n][t16][ks][lane][8]
  u16* q_b    = (u16*)(ws + 27262976);   // 16 MB [b][h][i][d]
  u16* k_f    = (u16*)(ws + 44040192);   // 16 MB frag order [bn][j16][ks][lane][8]
  u16* v_f    = (u16*)(ws + 60817408);   // 16 MB frag order [bn][j16][dd][lane][4]
  u16* av_b   = w_b;

  cast_w_k<<<8192, 256, 0, stream>>>(w, w_b);
  transpose_cast_k<<<dim3(96, 32), 256, 0, stream>>>(qkv_w, qkvw_t, 1024, 3072);
  transpose_cast_k<<<dim3(32, 32), 256, 0, stream>>>(o_w, ow_t, 1024, 1024);
  cast_remb_k<<<512, 256, 0, stream>>>(r_emb, remb_f);
  gemm_bt<0><<<dim3(24, 64), 256, 0, stream>>>(w_b, qkvw_t, 1024, q_b, k_f, v_f, nullptr, nullptr);
  attn_k<<<dim3(2048), 256, 0, stream>>>(q_b, k_f, v_f, remb_f, r_bias, r_wb, av_b);
  gemm_bt<1><<<dim3(8, 64), 256, 0, stream>>>(av_b, ow_t, 1024, nullptr, nullptr, nullptr, w, out);
  ln_k<<<8192, 256, 0, stream>>>(out, ln_g, ln_b);
}

// Round 7
// 224.304 us; speedup vs baseline: 1.8586x; 1.1030x over previous
//
#include <hip/hip_runtime.h>

typedef unsigned short u16;
typedef __attribute__((ext_vector_type(8))) short bf16x8;
typedef __attribute__((ext_vector_type(4))) short bf16x4;
typedef __attribute__((ext_vector_type(4))) float f32x4;
typedef __attribute__((ext_vector_type(4))) unsigned short u16x4;

// Problem constants (fixed by the reference)
#define SEQ 1024
#define BSZ 8
#define NHD 16
#define DHD 64
#define DMODEL 1024

__device__ __forceinline__ u16 f2bf(float x) {
  unsigned u = __float_as_uint(x);
  return (u16)((u + 0x7fffu + ((u >> 16) & 1u)) >> 16);  // RNE
}
__device__ __forceinline__ float bf2f(u16 h) {
  return __uint_as_float(((unsigned)h) << 16);
}

typedef const __attribute__((address_space(1))) unsigned int gu32_t;
typedef __attribute__((address_space(3))) unsigned int lu32_t;
__device__ __forceinline__ void gload16(const void* g, void* l) {
  __builtin_amdgcn_global_load_lds((gu32_t*)g, (lu32_t*)l, 16, 0, 0);
}

// ---------------- cast / transpose kernels ----------------
__global__ void cast_w_k(const float* __restrict__ in, u16* __restrict__ out) {
  size_t i = ((size_t)blockIdx.x * 256 + threadIdx.x) * 4;
  float4 v = *(const float4*)(in + i);
  u16x4 o;
  o[0] = f2bf(v.x); o[1] = f2bf(v.y); o[2] = f2bf(v.z); o[3] = f2bf(v.w);
  *(u16x4*)(out + i) = o;
}

// in [R][C] f32 -> out [C][R] bf16
__global__ void transpose_cast_k(const float* __restrict__ in, u16* __restrict__ out,
                                 int R, int C) {
  __shared__ float tile[32][33];
  int tx = threadIdx.x & 31, ty = threadIdx.x >> 5;
  int bx = blockIdx.x * 32, by = blockIdx.y * 32;
#pragma unroll
  for (int rr = ty; rr < 32; rr += 8)
    tile[rr][tx] = in[(size_t)(by + rr) * C + bx + tx];
  __syncthreads();
#pragma unroll
  for (int rr = ty; rr < 32; rr += 8)
    out[(size_t)(bx + rr) * R + by + tx] = f2bf(tile[tx][rr]);
}

// r_emb [j][n][d] f32 -> MFMA-A-fragment order:
// rf[n][t16][ks][lane][8], lane = (t&15) | ((d>>3)&3)<<4, elems d&7
__global__ void cast_remb_k(const float* __restrict__ in, u16* __restrict__ out) {
  int t0 = blockIdx.x * 256 + threadIdx.x;  // (j*16+n)*8 + db
  int jn = t0 >> 3, db = t0 & 7;            // db: which 8-d octet
  int j = jn >> 4, n = jn & 15;
  const float* src = in + (size_t)jn * 64 + db * 8;
  u16* dst = out + (size_t)n * 65536 + (size_t)(j >> 4) * 1024 + (db >> 2) * 512 +
             (((j & 15) | ((db & 3) << 4)) << 3);
#pragma unroll
  for (int e = 0; e < 8; ++e) dst[e] = f2bf(src[e]);
}

// c[n][t] = r_w_bias[n] . r_emb[t][n][:]  (f32, exact)
__global__ void cvec_k(const float* __restrict__ remb, const float* __restrict__ rwb,
                       float* __restrict__ cv) {
  int idx = blockIdx.x * 256 + threadIdx.x;  // n*1024 + t
  int n = idx >> 10, t = idx & 1023;
  const float* src = remb + (size_t)(t * 16 + n) * 64;
  const float* wb = rwb + n * 64;
  float s = 0.f;
#pragma unroll
  for (int d = 0; d < 64; ++d) s += src[d] * wb[d];
  cv[idx] = s;
}

// ---------------- GEMM: C[M,N] = A[M,K] @ Bt[N,K]^T  (bf16, 128x128 tile) ----------------
// EPI 0: scatter q normal [b][h][i][d]; K and V in MFMA-fragment order (see attn_k).
// EPI 1: yout = resid + C (f32).
template <int EPI>
__global__ __launch_bounds__(256) void gemm_bt(
    const u16* __restrict__ A, const u16* __restrict__ Bt, int K,
    u16* __restrict__ q_o, u16* __restrict__ k_o, u16* __restrict__ v_o,
    const float* __restrict__ resid, float* __restrict__ yout) {
  __shared__ __attribute__((aligned(16))) u16 ldsA[2][4096];  // [128 rows][32 k]
  __shared__ __attribute__((aligned(16))) u16 ldsB[2][4096];
  const int tid = threadIdx.x;
  const int wid = tid >> 6, l = tid & 63;
  const int l15 = l & 15, lg = l >> 4;
  const int bm = blockIdx.y, bn = blockIdx.x;
  const int wm = wid & 1, wn = wid >> 1;
  const size_t ldb = (size_t)K * 2;  // row bytes

  const char* aA = (const char*)A + (size_t)(bm * 128 + wid * 32 + (l >> 2)) * ldb + (l & 3) * 16;
  const char* aB = (const char*)Bt + (size_t)(bn * 128 + wid * 32 + (l >> 2)) * ldb + (l & 3) * 16;

  auto stage = [&](int buf, int kt) {
    const char* sa = aA + (size_t)kt * 64;
    const char* sb = aB + (size_t)kt * 64;
    char* la = (char*)&ldsA[buf][wid * 1024];
    char* lb = (char*)&ldsB[buf][wid * 1024];
    gload16(sa, la);
    gload16(sa + 16 * ldb, la + 1024);
    gload16(sb, lb);
    gload16(sb + 16 * ldb, lb + 1024);
  };

  f32x4 acc[4][4] = {};
  stage(0, 0);
  __syncthreads();
  const int NT = K >> 5;
  for (int t = 0; t < NT; ++t) {
    int cur = t & 1;
    if (t + 1 < NT) stage(cur ^ 1, t + 1);
    bf16x8 af[4], bfr[4];
#pragma unroll
    for (int mi = 0; mi < 4; ++mi)
      af[mi] = *(const bf16x8*)&ldsA[cur][(wm * 64 + mi * 16 + l15) * 32 + lg * 8];
#pragma unroll
    for (int ni = 0; ni < 4; ++ni)
      bfr[ni] = *(const bf16x8*)&ldsB[cur][(wn * 64 + ni * 16 + l15) * 32 + lg * 8];
#pragma unroll
    for (int mi = 0; mi < 4; ++mi)
#pragma unroll
      for (int ni = 0; ni < 4; ++ni)
        acc[mi][ni] = __builtin_amdgcn_mfma_f32_16x16x32_bf16(af[mi], bfr[ni], acc[mi][ni], 0, 0, 0);
    __syncthreads();
  }

  if (EPI == 0) {
#pragma unroll
    for (int mi = 0; mi < 4; ++mi)
#pragma unroll
      for (int ni = 0; ni < 4; ++ni) {
        int c = bn * 128 + wn * 64 + ni * 16 + l15;
        int which = c >> 10, rem = c & 1023, h = rem >> 6, d = rem & 63;
        u16* dst = which == 0 ? q_o : (which == 1 ? k_o : v_o);
#pragma unroll
        for (int r = 0; r < 4; ++r) {
          int rg = bm * 128 + wm * 64 + mi * 16 + lg * 4 + r;
          int i = rg >> 3, bb = rg & 7;
          int bn2 = bb * 16 + h;
          size_t idx;
          if (which == 0) {
            idx = ((size_t)bn2 * 1024 + i) * 64 + d;
          } else if (which == 1) {
            // K frag: [bn][j16][ks][lane][8]
            idx = (size_t)bn2 * 65536 + (size_t)(i >> 4) * 1024 + (d >> 5) * 512 +
                  (((i & 15) | (((d >> 3) & 3) << 4)) << 3) + (d & 7);
          } else {
            // V frag: [bn][j16][dd][lane][4]
            idx = (size_t)bn2 * 65536 + (size_t)(i >> 4) * 1024 + (d >> 4) * 256 +
                  (((d & 15) | (((i >> 2) & 3) << 4)) << 2) + (i & 3);
          }
          dst[idx] = f2bf(acc[mi][ni][r]);
        }
      }
  } else {
#pragma unroll
    for (int mi = 0; mi < 4; ++mi)
#pragma unroll
      for (int ni = 0; ni < 4; ++ni) {
        int c = bn * 128 + wn * 64 + ni * 16 + l15;
#pragma unroll
        for (int r = 0; r < 4; ++r) {
          int rg = bm * 128 + wm * 64 + mi * 16 + lg * 4 + r;
          size_t off = (size_t)rg * 1024 + c;
          yout[off] = resid[off] + acc[mi][ni][r];
        }
      }
  }
}

// ---------------- fused causal rel-attention (barrier-free, frag-direct) ----------------
// R5 structure (proven replay-safe) + cvec fold (single qw fragment set) +
// launch_bounds(256,4): ~128 VGPR so the compiler can keep the tile's
// K/remb/V loads in flight instead of serializing (R5 compiled at 40 VGPR).
// score = 0.125*( (K.(q+rwb))^T + (q+rwb).r_emb[t] + r_bias[t] - rwb.r_emb[t] )
__global__ __launch_bounds__(256, 4) void attn_k(
    const u16* __restrict__ qg, const u16* __restrict__ kf, const u16* __restrict__ vf,
    const u16* __restrict__ rf, const float* __restrict__ rbias,
    const float* __restrict__ cvec, const float* __restrict__ rwb,
    u16* __restrict__ av) {
  __shared__ __attribute__((aligned(16))) float Elds[4][16][84];
  __shared__ __attribute__((aligned(16))) float rb[1088];

  const int tid = threadIdx.x;
  const int wid = tid >> 6, l = tid & 63;
  const int l15 = l & 15, lg = l >> 4;
  const int id = blockIdx.x;
  const int qblk = 15 - (id >> 7);   // longest-first dispatch
  const int n = (id & 7) | (((id >> 3) & 1) << 3);  // id%8 keys head%8 (XCD grouping)
  const int b = (id >> 4) & 7;
  const int bn = b * 16 + n;
  const int ib = qblk * 64;
  const int iw = ib + wid * 16;

  for (int idx = tid; idx < 1088; idx += 256)
    rb[idx] = (idx < 1024) ? (rbias[idx * 16 + n] - cvec[n * 1024 + idx]) : 0.f;

  // single Q fragment set with r_w_bias folded (used for both E and S)
  const u16* qrow = qg + ((size_t)bn * 1024 + iw + l15) * 64;
  const float* wbp = rwb + n * 64;
  bf16x8 qr0 = *(const bf16x8*)(qrow + lg * 8);
  bf16x8 qr1 = *(const bf16x8*)(qrow + 32 + lg * 8);
  bf16x8 qw0, qw1;
#pragma unroll
  for (int e = 0; e < 8; ++e) {
    qw0[e] = (short)f2bf(bf2f((u16)qr0[e]) + wbp[lg * 8 + e]);
    qw1[e] = (short)f2bf(bf2f((u16)qr1[e]) + wbp[32 + lg * 8 + e]);
  }

  f32x4 oacc[4] = {};
  float m_run = -1e30f, l_run = 0.f;

  // per-lane fragment pointers (lane-major frag layouts, fully coalesced)
  const u16* kfp = kf + (size_t)bn * 65536 + l * 8;
  const u16* vfp = vf + (size_t)bn * 65536 + l * 4;
  const u16* rfp = rf + (size_t)n * 65536 + l * 8;

  __syncthreads();  // rb visible (the only barrier)

  const int njt = qblk + 1;
  for (int jt = 0; jt < njt; ++jt) {
    const int jb = jt * 64;

    // ---- K fragments: 8 coalesced 1KB loads ----
    const u16* kt = kfp + jt * 4096;
    bf16x8 kf00 = *(const bf16x8*)(kt);
    bf16x8 kf01 = *(const bf16x8*)(kt + 512);
    bf16x8 kf10 = *(const bf16x8*)(kt + 1024);
    bf16x8 kf11 = *(const bf16x8*)(kt + 1536);
    bf16x8 kf20 = *(const bf16x8*)(kt + 2048);
    bf16x8 kf21 = *(const bf16x8*)(kt + 2560);
    bf16x8 kf30 = *(const bf16x8*)(kt + 3072);
    bf16x8 kf31 = *(const bf16x8*)(kt + 3584);

    // ---- E[i,t] = (q+rwb).r_emb[t], t in [tb,tb+80), (rb-c) folded, f32 LDS ----
    const int tb = jb - iw + 1008;
    const int tb16 = tb >> 4;
#pragma unroll
    for (int f = 0; f < 5; ++f) {
      int t16 = tb16 + f;
      if (t16 > 63) t16 = 63;  // >1023 rows are masked region anyway
      const u16* rr = rfp + t16 * 1024;
      bf16x8 ra0 = *(const bf16x8*)(rr);
      bf16x8 ra1 = *(const bf16x8*)(rr + 512);
      f32x4 et = {};
      et = __builtin_amdgcn_mfma_f32_16x16x32_bf16(ra0, qw0, et, 0, 0, 0);
      et = __builtin_amdgcn_mfma_f32_16x16x32_bf16(ra1, qw1, et, 0, 0, 0);
      f32x4 rb4 = *(const f32x4*)&rb[tb + f * 16 + lg * 4];
      et = et + rb4;
      *(f32x4*)&Elds[wid][l15][f * 16 + lg * 4] = et;
    }

    // ---- S^T = K.(q+rwb) : acc row j=lg*4+r, col i=l15 ----
    f32x4 st[4];
    __builtin_amdgcn_s_setprio(1);
    {
      f32x4 a;
      a = __builtin_amdgcn_mfma_f32_16x16x32_bf16(kf00, qw0, (f32x4){}, 0, 0, 0);
      st[0] = __builtin_amdgcn_mfma_f32_16x16x32_bf16(kf01, qw1, a, 0, 0, 0);
      a = __builtin_amdgcn_mfma_f32_16x16x32_bf16(kf10, qw0, (f32x4){}, 0, 0, 0);
      st[1] = __builtin_amdgcn_mfma_f32_16x16x32_bf16(kf11, qw1, a, 0, 0, 0);
      a = __builtin_amdgcn_mfma_f32_16x16x32_bf16(kf20, qw0, (f32x4){}, 0, 0, 0);
      st[2] = __builtin_amdgcn_mfma_f32_16x16x32_bf16(kf21, qw1, a, 0, 0, 0);
      a = __builtin_amdgcn_mfma_f32_16x16x32_bf16(kf30, qw0, (f32x4){}, 0, 0, 0);
      st[3] = __builtin_amdgcn_mfma_f32_16x16x32_bf16(kf31, qw1, a, 0, 0, 0);
    }
    __builtin_amdgcn_s_setprio(0);

    // ---- V-frag group for dd=0 (coalesced 512B loads; hide under softmax) ----
    const u16* vt0 = vfp + jt * 4096;
    bf16x4 va0 = *(const bf16x4*)(vt0);
    bf16x4 va1 = *(const bf16x4*)(vt0 + 1024);
    bf16x4 va2 = *(const bf16x4*)(vt0 + 2048);
    bf16x4 va3 = *(const bf16x4*)(vt0 + 3072);

    // ---- softmax (scores in-place in st) ----
    const bool domask = (jb == ib);  // only the diagonal tile needs masking
    float tmax = -1e30f;
#pragma unroll
    for (int jj = 0; jj < 4; ++jj)
#pragma unroll
      for (int r2 = 0; r2 < 4; ++r2) {
        int jl = jj * 16 + lg * 4 + r2;
        float v = st[jj][r2] + Elds[wid][l15][jl - l15 + 15];
        v *= 0.125f;
        if (domask && (jl > wid * 16 + l15)) v = -1e30f;
        st[jj][r2] = v;
        tmax = fmaxf(tmax, v);
      }
    tmax = fmaxf(tmax, __shfl_xor(tmax, 16));
    tmax = fmaxf(tmax, __shfl_xor(tmax, 32));

    // defer-max (T13): only rescale when the running max grew by > 8
    if (!__all(tmax - m_run <= 8.0f)) {
      float m_new = fmaxf(m_run, tmax);
      float fac = __expf(m_run - m_new);
      m_run = m_new;
      l_run *= fac;
      float fo[4];
#pragma unroll
      for (int r2 = 0; r2 < 4; ++r2) fo[r2] = __shfl(fac, (l & 48) | (lg * 4 + r2));
#pragma unroll
      for (int dd = 0; dd < 4; ++dd)
#pragma unroll
        for (int r2 = 0; r2 < 4; ++r2) oacc[dd][r2] *= fo[r2];
    }

    float psum = 0.f;
    bf16x4 pa[4];
#pragma unroll
    for (int jj = 0; jj < 4; ++jj)
#pragma unroll
      for (int r2 = 0; r2 < 4; ++r2) {
        float p = __expf(st[jj][r2] - m_run);
        psum += p;
        pa[jj][r2] = (short)f2bf(p);
      }
    psum += __shfl_xor(psum, 16);
    psum += __shfl_xor(psum, 32);
    l_run += psum;

    // ---- PV: P (S^T-acc layout) is the 16x16x16 A-fragment; V groups pipelined ----
    __builtin_amdgcn_s_setprio(1);
    {
      const u16* vt1 = vt0 + 256;  // dd=1
      bf16x4 vb0 = *(const bf16x4*)(vt1);
      bf16x4 vb1 = *(const bf16x4*)(vt1 + 1024);
      bf16x4 vb2 = *(const bf16x4*)(vt1 + 2048);
      bf16x4 vb3 = *(const bf16x4*)(vt1 + 3072);
      oacc[0] = __builtin_amdgcn_mfma_f32_16x16x16bf16_1k(pa[0], va0, oacc[0], 0, 0, 0);
      oacc[0] = __builtin_amdgcn_mfma_f32_16x16x16bf16_1k(pa[1], va1, oacc[0], 0, 0, 0);
      oacc[0] = __builtin_amdgcn_mfma_f32_16x16x16bf16_1k(pa[2], va2, oacc[0], 0, 0, 0);
      oacc[0] = __builtin_amdgcn_mfma_f32_16x16x16bf16_1k(pa[3], va3, oacc[0], 0, 0, 0);
      const u16* vt2 = vt0 + 512;  // dd=2
      va0 = *(const bf16x4*)(vt2);
      va1 = *(const bf16x4*)(vt2 + 1024);
      va2 = *(const bf16x4*)(vt2 + 2048);
      va3 = *(const bf16x4*)(vt2 + 3072);
      oacc[1] = __builtin_amdgcn_mfma_f32_16x16x16bf16_1k(pa[0], vb0, oacc[1], 0, 0, 0);
      oacc[1] = __builtin_amdgcn_mfma_f32_16x16x16bf16_1k(pa[1], vb1, oacc[1], 0, 0, 0);
      oacc[1] = __builtin_amdgcn_mfma_f32_16x16x16bf16_1k(pa[2], vb2, oacc[1], 0, 0, 0);
      oacc[1] = __builtin_amdgcn_mfma_f32_16x16x16bf16_1k(pa[3], vb3, oacc[1], 0, 0, 0);
      const u16* vt3 = vt0 + 768;  // dd=3
      vb0 = *(const bf16x4*)(vt3);
      vb1 = *(const bf16x4*)(vt3 + 1024);
      vb2 = *(const bf16x4*)(vt3 + 2048);
      vb3 = *(const bf16x4*)(vt3 + 3072);
      oacc[2] = __builtin_amdgcn_mfma_f32_16x16x16bf16_1k(pa[0], va0, oacc[2], 0, 0, 0);
      oacc[2] = __builtin_amdgcn_mfma_f32_16x16x16bf16_1k(pa[1], va1, oacc[2], 0, 0, 0);
      oacc[2] = __builtin_amdgcn_mfma_f32_16x16x16bf16_1k(pa[2], va2, oacc[2], 0, 0, 0);
      oacc[2] = __builtin_amdgcn_mfma_f32_16x16x16bf16_1k(pa[3], va3, oacc[2], 0, 0, 0);
      oacc[3] = __builtin_amdgcn_mfma_f32_16x16x16bf16_1k(pa[0], vb0, oacc[3], 0, 0, 0);
      oacc[3] = __builtin_amdgcn_mfma_f32_16x16x16bf16_1k(pa[1], vb1, oacc[3], 0, 0, 0);
      oacc[3] = __builtin_amdgcn_mfma_f32_16x16x16bf16_1k(pa[2], vb2, oacc[3], 0, 0, 0);
      oacc[3] = __builtin_amdgcn_mfma_f32_16x16x16bf16_1k(pa[3], vb3, oacc[3], 0, 0, 0);
    }
    __builtin_amdgcn_s_setprio(0);
  }

  float linv = 1.f / l_run;
  float io[4];
#pragma unroll
  for (int r2 = 0; r2 < 4; ++r2) io[r2] = __shfl(linv, (l & 48) | (lg * 4 + r2));
#pragma unroll
  for (int dd = 0; dd < 4; ++dd)
#pragma unroll
    for (int r2 = 0; r2 < 4; ++r2) {
      int ig = iw + lg * 4 + r2;
      av[((size_t)ig * 8 + b) * 1024 + n * 64 + dd * 16 + l15] = f2bf(oacc[dd][r2] * io[r2]);
    }
}

// ---------------- in-place LayerNorm over rows of 1024 ----------------
__global__ void ln_k(float* __restrict__ y, const float* __restrict__ g,
                     const float* __restrict__ be) {
  const int row = blockIdx.x, tid = threadIdx.x;
  float* p = y + (size_t)row * 1024;
  float4 v = ((const float4*)p)[tid];
  float s1 = v.x + v.y + v.z + v.w;
  float s2 = v.x * v.x + v.y * v.y + v.z * v.z + v.w * v.w;
#pragma unroll
  for (int mk = 1; mk < 64; mk <<= 1) {
    s1 += __shfl_xor(s1, mk);
    s2 += __shfl_xor(s2, mk);
  }
  __shared__ float as1[4], as2[4];
  if ((tid & 63) == 0) { as1[tid >> 6] = s1; as2[tid >> 6] = s2; }
  __syncthreads();
  s1 = as1[0] + as1[1] + as1[2] + as1[3];
  s2 = as2[0] + as2[1] + as2[2] + as2[3];
  float mu = s1 * (1.f / 1024.f);
  float var = s2 * (1.f / 1024.f) - mu * mu;
  float rs = rsqrtf(var + 1e-5f);
  float4 gg = ((const float4*)g)[tid];
  float4 bb = ((const float4*)be)[tid];
  float4 o;
  o.x = (v.x - mu) * rs * gg.x + bb.x;
  o.y = (v.y - mu) * rs * gg.y + bb.y;
  o.z = (v.z - mu) * rs * gg.z + bb.z;
  o.w = (v.w - mu) * rs * gg.w + bb.w;
  ((float4*)p)[tid] = o;
}

extern "C" void kernel_launch(void* const* d_in, const int* in_sizes, int n_in,
                              void* d_out, int out_size, void* d_ws, size_t ws_size,
                              hipStream_t stream) {
  (void)in_sizes; (void)n_in; (void)out_size; (void)ws_size;
  const float* w      = (const float*)d_in[0];
  const float* r_emb  = (const float*)d_in[1];
  const float* r_wb   = (const float*)d_in[2];
  const float* r_bias = (const float*)d_in[3];
  const float* qkv_w  = (const float*)d_in[4];
  const float* o_w    = (const float*)d_in[5];
  const float* ln_g   = (const float*)d_in[6];
  const float* ln_b   = (const float*)d_in[7];
  float* out = (float*)d_out;
  char* ws = (char*)d_ws;

  // workspace layout (bytes); total ~77.7 MB
  u16* w_b    = (u16*)(ws + 0);          // 16 MB; reused as attn_vec after QKV GEMM
  u16* qkvw_t = (u16*)(ws + 16777216);   // 6 MB  [3072][1024]
  u16* ow_t   = (u16*)(ws + 23068672);   // 2 MB  [1024][1024]
  u16* remb_f = (u16*)(ws + 25165824);   // 2 MB  frag order [n][t16][ks][lane][8]
  u16* q_b    = (u16*)(ws + 27262976);   // 16 MB [b][h][i][d]
  u16* k_f    = (u16*)(ws + 44040192);   // 16 MB frag order [bn][j16][ks][lane][8]
  u16* v_f    = (u16*)(ws + 60817408);   // 16 MB frag order [bn][j16][dd][lane][4]
  float* cvb  = (float*)(ws + 77594624); // 64 KB [n][t]
  u16* av_b   = w_b;

  cast_w_k<<<8192, 256, 0, stream>>>(w, w_b);
  transpose_cast_k<<<dim3(96, 32), 256, 0, stream>>>(qkv_w, qkvw_t, 1024, 3072);
  transpose_cast_k<<<dim3(32, 32), 256, 0, stream>>>(o_w, ow_t, 1024, 1024);
  cast_remb_k<<<512, 256, 0, stream>>>(r_emb, remb_f);
  cvec_k<<<64, 256, 0, stream>>>(r_emb, r_wb, cvb);
  gemm_bt<0><<<dim3(24, 64), 256, 0, stream>>>(w_b, qkvw_t, 1024, q_b, k_f, v_f, nullptr, nullptr);
  attn_k<<<dim3(2048), 256, 0, stream>>>(q_b, k_f, v_f, remb_f, r_bias, cvb, r_wb, av_b);
  gemm_bt<1><<<dim3(8, 64), 256, 0, stream>>>(av_b, ow_t, 1024, nullptr, nullptr, nullptr, w, out);
  ln_k<<<8192, 256, 0, stream>>>(out, ln_g, ln_b);
}

// Round 8
// 205.909 us; speedup vs baseline: 2.0247x; 1.0893x over previous
//
#include <hip/hip_runtime.h>

typedef unsigned short u16;
typedef __attribute__((ext_vector_type(8))) short bf16x8;
typedef __attribute__((ext_vector_type(4))) short bf16x4;
typedef __attribute__((ext_vector_type(4))) float f32x4;
typedef __attribute__((ext_vector_type(4))) unsigned short u16x4;

// Problem constants (fixed by the reference)
#define SEQ 1024
#define BSZ 8
#define NHD 16
#define DHD 64
#define DMODEL 1024

__device__ __forceinline__ u16 f2bf(float x) {
  unsigned u = __float_as_uint(x);
  return (u16)((u + 0x7fffu + ((u >> 16) & 1u)) >> 16);  // RNE
}
__device__ __forceinline__ float bf2f(u16 h) {
  return __uint_as_float(((unsigned)h) << 16);
}

typedef const __attribute__((address_space(1))) unsigned int gu32_t;
typedef __attribute__((address_space(3))) unsigned int lu32_t;
__device__ __forceinline__ void gload16(const void* g, void* l) {
  __builtin_amdgcn_global_load_lds((gu32_t*)g, (lu32_t*)l, 16, 0, 0);
}

// ---------------- cast / transpose kernels ----------------
__global__ void cast_w_k(const float* __restrict__ in, u16* __restrict__ out) {
  size_t i = ((size_t)blockIdx.x * 256 + threadIdx.x) * 4;
  float4 v = *(const float4*)(in + i);
  u16x4 o;
  o[0] = f2bf(v.x); o[1] = f2bf(v.y); o[2] = f2bf(v.z); o[3] = f2bf(v.w);
  *(u16x4*)(out + i) = o;
}

// in [R][C] f32 -> out [C][R] bf16
__global__ void transpose_cast_k(const float* __restrict__ in, u16* __restrict__ out,
                                 int R, int C) {
  __shared__ float tile[32][33];
  int tx = threadIdx.x & 31, ty = threadIdx.x >> 5;
  int bx = blockIdx.x * 32, by = blockIdx.y * 32;
#pragma unroll
  for (int rr = ty; rr < 32; rr += 8)
    tile[rr][tx] = in[(size_t)(by + rr) * C + bx + tx];
  __syncthreads();
#pragma unroll
  for (int rr = ty; rr < 32; rr += 8)
    out[(size_t)(bx + rr) * R + by + tx] = f2bf(tile[tx][rr]);
}

// r_emb [j][n][d] f32 -> MFMA-A-fragment order:
// rf[n][t16][ks][lane][8], lane = (t&15) | ((d>>3)&3)<<4, elems d&7
__global__ void cast_remb_k(const float* __restrict__ in, u16* __restrict__ out) {
  int t0 = blockIdx.x * 256 + threadIdx.x;  // (j*16+n)*8 + db
  int jn = t0 >> 3, db = t0 & 7;            // db: which 8-d octet
  int j = jn >> 4, n = jn & 15;
  const float* src = in + (size_t)jn * 64 + db * 8;
  u16* dst = out + (size_t)n * 65536 + (size_t)(j >> 4) * 1024 + (db >> 2) * 512 +
             (((j & 15) | ((db & 3) << 4)) << 3);
#pragma unroll
  for (int e = 0; e < 8; ++e) dst[e] = f2bf(src[e]);
}

// c[n][t] = r_w_bias[n] . r_emb[t][n][:]  (f32, exact)
__global__ void cvec_k(const float* __restrict__ remb, const float* __restrict__ rwb,
                       float* __restrict__ cv) {
  int idx = blockIdx.x * 256 + threadIdx.x;  // n*1024 + t
  int n = idx >> 10, t = idx & 1023;
  const float* src = remb + (size_t)(t * 16 + n) * 64;
  const float* wb = rwb + n * 64;
  float s = 0.f;
#pragma unroll
  for (int d = 0; d < 64; ++d) s += src[d] * wb[d];
  cv[idx] = s;
}

// ---------------- GEMM: C[M,N] = A[M,K] @ Bt[N,K]^T  (bf16, 128x128 tile) ----------------
// EPI 0: scatter q normal [b][h][i][d]; K and V in MFMA-fragment order (see attn_k).
// EPI 1: yout = resid + C (f32).
template <int EPI>
__global__ __launch_bounds__(256) void gemm_bt(
    const u16* __restrict__ A, const u16* __restrict__ Bt, int K,
    u16* __restrict__ q_o, u16* __restrict__ k_o, u16* __restrict__ v_o,
    const float* __restrict__ resid, float* __restrict__ yout) {
  __shared__ __attribute__((aligned(16))) u16 ldsA[2][4096];  // [128 rows][32 k]
  __shared__ __attribute__((aligned(16))) u16 ldsB[2][4096];
  const int tid = threadIdx.x;
  const int wid = tid >> 6, l = tid & 63;
  const int l15 = l & 15, lg = l >> 4;
  const int bm = blockIdx.y, bn = blockIdx.x;
  const int wm = wid & 1, wn = wid >> 1;
  const size_t ldb = (size_t)K * 2;  // row bytes

  const char* aA = (const char*)A + (size_t)(bm * 128 + wid * 32 + (l >> 2)) * ldb + (l & 3) * 16;
  const char* aB = (const char*)Bt + (size_t)(bn * 128 + wid * 32 + (l >> 2)) * ldb + (l & 3) * 16;

  auto stage = [&](int buf, int kt) {
    const char* sa = aA + (size_t)kt * 64;
    const char* sb = aB + (size_t)kt * 64;
    char* la = (char*)&ldsA[buf][wid * 1024];
    char* lb = (char*)&ldsB[buf][wid * 1024];
    gload16(sa, la);
    gload16(sa + 16 * ldb, la + 1024);
    gload16(sb, lb);
    gload16(sb + 16 * ldb, lb + 1024);
  };

  f32x4 acc[4][4] = {};
  stage(0, 0);
  __syncthreads();
  const int NT = K >> 5;
  for (int t = 0; t < NT; ++t) {
    int cur = t & 1;
    if (t + 1 < NT) stage(cur ^ 1, t + 1);
    bf16x8 af[4], bfr[4];
#pragma unroll
    for (int mi = 0; mi < 4; ++mi)
      af[mi] = *(const bf16x8*)&ldsA[cur][(wm * 64 + mi * 16 + l15) * 32 + lg * 8];
#pragma unroll
    for (int ni = 0; ni < 4; ++ni)
      bfr[ni] = *(const bf16x8*)&ldsB[cur][(wn * 64 + ni * 16 + l15) * 32 + lg * 8];
#pragma unroll
    for (int mi = 0; mi < 4; ++mi)
#pragma unroll
      for (int ni = 0; ni < 4; ++ni)
        acc[mi][ni] = __builtin_amdgcn_mfma_f32_16x16x32_bf16(af[mi], bfr[ni], acc[mi][ni], 0, 0, 0);
    __syncthreads();
  }

  if (EPI == 0) {
#pragma unroll
    for (int mi = 0; mi < 4; ++mi)
#pragma unroll
      for (int ni = 0; ni < 4; ++ni) {
        int c = bn * 128 + wn * 64 + ni * 16 + l15;
        int which = c >> 10, rem = c & 1023, h = rem >> 6, d = rem & 63;
        u16* dst = which == 0 ? q_o : (which == 1 ? k_o : v_o);
#pragma unroll
        for (int r = 0; r < 4; ++r) {
          int rg = bm * 128 + wm * 64 + mi * 16 + lg * 4 + r;
          int i = rg >> 3, bb = rg & 7;
          int bn2 = bb * 16 + h;
          size_t idx;
          if (which == 0) {
            idx = ((size_t)bn2 * 1024 + i) * 64 + d;
          } else if (which == 1) {
            // K frag: [bn][j16][ks][lane][8]
            idx = (size_t)bn2 * 65536 + (size_t)(i >> 4) * 1024 + (d >> 5) * 512 +
                  (((i & 15) | (((d >> 3) & 3) << 4)) << 3) + (d & 7);
          } else {
            // V frag: [bn][j16][dd][lane][4]
            idx = (size_t)bn2 * 65536 + (size_t)(i >> 4) * 1024 + (d >> 4) * 256 +
                  (((d & 15) | (((i >> 2) & 3) << 4)) << 2) + (i & 3);
          }
          dst[idx] = f2bf(acc[mi][ni][r]);
        }
      }
  } else {
#pragma unroll
    for (int mi = 0; mi < 4; ++mi)
#pragma unroll
      for (int ni = 0; ni < 4; ++ni) {
        int c = bn * 128 + wn * 64 + ni * 16 + l15;
#pragma unroll
        for (int r = 0; r < 4; ++r) {
          int rg = bm * 128 + wm * 64 + mi * 16 + lg * 4 + r;
          size_t off = (size_t)rg * 1024 + c;
          yout[off] = resid[off] + acc[mi][ni][r];
        }
      }
  }
}

// ---------------- fused causal rel-attention (barrier-free, 32 q-rows/wave) ----------
// Block: 128 q-rows (4 waves x 32 rows as 2x16 subgroups A/B), KV tiles of 64.
// Subgroups SHARE the K and V fragments (loads per compute halve); E windows
// overlap by 64 -> 6 r_emb frags cover both. A 32-row wave span sits inside one
// 64-tile, so only the LAST tile needs masking (both diagonals live there).
// Waves are barrier-free and loop to their OWN njt. Longest blocks first.
// score = 0.125*( (K.(q+rwb))^T + (q+rwb).r_emb[t] + r_bias[t] - rwb.r_emb[t] )
__global__ __launch_bounds__(256, 3) void attn_k(
    const u16* __restrict__ qg, const u16* __restrict__ kf, const u16* __restrict__ vf,
    const u16* __restrict__ rf, const float* __restrict__ rbias,
    const float* __restrict__ cvec, const float* __restrict__ rwb,
    u16* __restrict__ av) {
  __shared__ __attribute__((aligned(16))) float EldsA[4][16][84];
  __shared__ __attribute__((aligned(16))) float EldsB[4][16][84];
  __shared__ __attribute__((aligned(16))) float rb[1088];

  const int tid = threadIdx.x;
  const int wid = tid >> 6, l = tid & 63;
  const int l15 = l & 15, lg = l >> 4;
  const int id = blockIdx.x;
  const int qblk = 7 - (id >> 7);    // longest-first dispatch (128 rows/block)
  const int n = (id & 7) | (((id >> 3) & 1) << 3);  // id%8 keys head%8 (XCD grouping)
  const int b = (id >> 4) & 7;
  const int bn = b * 16 + n;
  const int ib = qblk * 128;
  const int iw = ib + wid * 32;      // wave base: subgroup A rows iw.., B rows iw+16..

  for (int idx = tid; idx < 1088; idx += 256)
    rb[idx] = (idx < 1024) ? (rbias[idx * 16 + n] - cvec[n * 1024 + idx]) : 0.f;

  // Q fragment sets (r_w_bias folded), one per subgroup
  const float* wbp = rwb + n * 64;
  const u16* qrowA = qg + ((size_t)bn * 1024 + iw + l15) * 64;
  const u16* qrowB = qrowA + 16 * 64;
  bf16x8 qa0 = *(const bf16x8*)(qrowA + lg * 8);
  bf16x8 qa1 = *(const bf16x8*)(qrowA + 32 + lg * 8);
  bf16x8 qb0 = *(const bf16x8*)(qrowB + lg * 8);
  bf16x8 qb1 = *(const bf16x8*)(qrowB + 32 + lg * 8);
  bf16x8 qwA0, qwA1, qwB0, qwB1;
#pragma unroll
  for (int e = 0; e < 8; ++e) {
    float w0 = wbp[lg * 8 + e], w1 = wbp[32 + lg * 8 + e];
    qwA0[e] = (short)f2bf(bf2f((u16)qa0[e]) + w0);
    qwA1[e] = (short)f2bf(bf2f((u16)qa1[e]) + w1);
    qwB0[e] = (short)f2bf(bf2f((u16)qb0[e]) + w0);
    qwB1[e] = (short)f2bf(bf2f((u16)qb1[e]) + w1);
  }

  f32x4 oaccA[4] = {}, oaccB[4] = {};
  float mA = -1e30f, lA = 0.f, mB = -1e30f, lB = 0.f;

  // per-lane fragment pointers (lane-major frag layouts, fully coalesced)
  const u16* kfp = kf + (size_t)bn * 65536 + l * 8;
  const u16* vfp = vf + (size_t)bn * 65536 + l * 4;
  const u16* rfp = rf + (size_t)n * 65536 + l * 8;

  const int dAm = (iw & 63) + l15;   // last-tile mask thresholds
  const int dBm = dAm + 16;

  __syncthreads();  // rb visible (the only barrier)

  const int njt = (iw >> 6) + 1;     // per-wave tile count (barrier-free)
  for (int jt = 0; jt < njt; ++jt) {
    const int jb = jt * 64;

    // ---- K fragments: 8 coalesced 1KB loads (shared by A and B) ----
    const u16* kt = kfp + jt * 4096;
    bf16x8 kk[8];
#pragma unroll
    for (int s = 0; s < 8; ++s) kk[s] = *(const bf16x8*)(kt + s * 512);

    // ---- E phase: 6 frags cover both subgroups' windows ----
    const int tbB = jb - iw - 16 + 1008;  // subgroup B window base (A = tbB+16)
    const int t16b = tbB >> 4;
#pragma unroll
    for (int f = 0; f < 6; ++f) {
      int t16 = t16b + f;
      if (t16 > 63) t16 = 63;  // >1023 rows are masked region anyway
      const u16* rr = rfp + t16 * 1024;
      bf16x8 ra0 = *(const bf16x8*)(rr);
      bf16x8 ra1 = *(const bf16x8*)(rr + 512);
      f32x4 rb4 = *(const f32x4*)&rb[tbB + f * 16 + lg * 4];
      if (f < 5) {
        f32x4 et = {};
        et = __builtin_amdgcn_mfma_f32_16x16x32_bf16(ra0, qwB0, et, 0, 0, 0);
        et = __builtin_amdgcn_mfma_f32_16x16x32_bf16(ra1, qwB1, et, 0, 0, 0);
        *(f32x4*)&EldsB[wid][l15][f * 16 + lg * 4] = et + rb4;
      }
      if (f >= 1) {
        f32x4 et = {};
        et = __builtin_amdgcn_mfma_f32_16x16x32_bf16(ra0, qwA0, et, 0, 0, 0);
        et = __builtin_amdgcn_mfma_f32_16x16x32_bf16(ra1, qwA1, et, 0, 0, 0);
        *(f32x4*)&EldsA[wid][l15][(f - 1) * 16 + lg * 4] = et + rb4;
      }
    }

    // ---- S^T = K.(q+rwb) for both subgroups (K regs shared, then dead) ----
    f32x4 stA[4], stB[4];
    __builtin_amdgcn_s_setprio(1);
#pragma unroll
    for (int jj = 0; jj < 4; ++jj) {
      f32x4 a = __builtin_amdgcn_mfma_f32_16x16x32_bf16(kk[jj * 2], qwA0, (f32x4){}, 0, 0, 0);
      stA[jj] = __builtin_amdgcn_mfma_f32_16x16x32_bf16(kk[jj * 2 + 1], qwA1, a, 0, 0, 0);
    }
#pragma unroll
    for (int jj = 0; jj < 4; ++jj) {
      f32x4 a = __builtin_amdgcn_mfma_f32_16x16x32_bf16(kk[jj * 2], qwB0, (f32x4){}, 0, 0, 0);
      stB[jj] = __builtin_amdgcn_mfma_f32_16x16x32_bf16(kk[jj * 2 + 1], qwB1, a, 0, 0, 0);
    }
    __builtin_amdgcn_s_setprio(0);

    // ---- V fragments: 16 coalesced 512B loads (shared; hide under softmax) ----
    const u16* vt0 = vfp + jt * 4096;
    bf16x4 vv[4][4];
#pragma unroll
    for (int jj = 0; jj < 4; ++jj)
#pragma unroll
      for (int dd = 0; dd < 4; ++dd)
        vv[jj][dd] = *(const bf16x4*)(vt0 + jj * 1024 + dd * 256);

    // ---- softmax (both subgroups) ----
    const bool domask = (jt == njt - 1);  // both diagonals live in the last tile
    float tmaxA = -1e30f, tmaxB = -1e30f;
#pragma unroll
    for (int jj = 0; jj < 4; ++jj)
#pragma unroll
      for (int r2 = 0; r2 < 4; ++r2) {
        int jl = jj * 16 + lg * 4 + r2;
        float va = stA[jj][r2] + EldsA[wid][l15][jl - l15 + 15];
        float vb = stB[jj][r2] + EldsB[wid][l15][jl - l15 + 15];
        va *= 0.125f; vb *= 0.125f;
        if (domask) {
          if (jl > dAm) va = -1e30f;
          if (jl > dBm) vb = -1e30f;
        }
        stA[jj][r2] = va; stB[jj][r2] = vb;
        tmaxA = fmaxf(tmaxA, va); tmaxB = fmaxf(tmaxB, vb);
      }
    tmaxA = fmaxf(tmaxA, __shfl_xor(tmaxA, 16));
    tmaxA = fmaxf(tmaxA, __shfl_xor(tmaxA, 32));
    tmaxB = fmaxf(tmaxB, __shfl_xor(tmaxB, 16));
    tmaxB = fmaxf(tmaxB, __shfl_xor(tmaxB, 32));

    // defer-max (T13), shared trigger for both subgroups
    if (!__all(fmaxf(tmaxA - mA, tmaxB - mB) <= 8.0f)) {
      float mnA = fmaxf(mA, tmaxA), mnB = fmaxf(mB, tmaxB);
      float facA = __expf(mA - mnA), facB = __expf(mB - mnB);
      mA = mnA; mB = mnB;
      lA *= facA; lB *= facB;
      float foA[4], foB[4];
#pragma unroll
      for (int r2 = 0; r2 < 4; ++r2) {
        foA[r2] = __shfl(facA, (l & 48) | (lg * 4 + r2));
        foB[r2] = __shfl(facB, (l & 48) | (lg * 4 + r2));
      }
#pragma unroll
      for (int dd = 0; dd < 4; ++dd)
#pragma unroll
        for (int r2 = 0; r2 < 4; ++r2) {
          oaccA[dd][r2] *= foA[r2];
          oaccB[dd][r2] *= foB[r2];
        }
    }

    float psA = 0.f, psB = 0.f;
    bf16x4 paA[4], paB[4];
#pragma unroll
    for (int jj = 0; jj < 4; ++jj)
#pragma unroll
      for (int r2 = 0; r2 < 4; ++r2) {
        float pA = __expf(stA[jj][r2] - mA);
        float pB = __expf(stB[jj][r2] - mB);
        psA += pA; psB += pB;
        paA[jj][r2] = (short)f2bf(pA);
        paB[jj][r2] = (short)f2bf(pB);
      }
    psA += __shfl_xor(psA, 16);
    psA += __shfl_xor(psA, 32);
    psB += __shfl_xor(psB, 16);
    psB += __shfl_xor(psB, 32);
    lA += psA; lB += psB;

    // ---- PV: P is the 16x16x16 A-fragment; V frags shared by A and B ----
    __builtin_amdgcn_s_setprio(1);
#pragma unroll
    for (int dd = 0; dd < 4; ++dd)
#pragma unroll
      for (int jj = 0; jj < 4; ++jj)
        oaccA[dd] = __builtin_amdgcn_mfma_f32_16x16x16bf16_1k(paA[jj], vv[jj][dd], oaccA[dd], 0, 0, 0);
#pragma unroll
    for (int dd = 0; dd < 4; ++dd)
#pragma unroll
      for (int jj = 0; jj < 4; ++jj)
        oaccB[dd] = __builtin_amdgcn_mfma_f32_16x16x16bf16_1k(paB[jj], vv[jj][dd], oaccB[dd], 0, 0, 0);
    __builtin_amdgcn_s_setprio(0);
  }

  float liA = 1.f / lA, liB = 1.f / lB;
  float ioA[4], ioB[4];
#pragma unroll
  for (int r2 = 0; r2 < 4; ++r2) {
    ioA[r2] = __shfl(liA, (l & 48) | (lg * 4 + r2));
    ioB[r2] = __shfl(liB, (l & 48) | (lg * 4 + r2));
  }
#pragma unroll
  for (int dd = 0; dd < 4; ++dd)
#pragma unroll
    for (int r2 = 0; r2 < 4; ++r2) {
      int igA = iw + lg * 4 + r2;
      av[((size_t)igA * 8 + b) * 1024 + n * 64 + dd * 16 + l15] = f2bf(oaccA[dd][r2] * ioA[r2]);
      int igB = igA + 16;
      av[((size_t)igB * 8 + b) * 1024 + n * 64 + dd * 16 + l15] = f2bf(oaccB[dd][r2] * ioB[r2]);
    }
}

// ---------------- in-place LayerNorm over rows of 1024 ----------------
__global__ void ln_k(float* __restrict__ y, const float* __restrict__ g,
                     const float* __restrict__ be) {
  const int row = blockIdx.x, tid = threadIdx.x;
  float* p = y + (size_t)row * 1024;
  float4 v = ((const float4*)p)[tid];
  float s1 = v.x + v.y + v.z + v.w;
  float s2 = v.x * v.x + v.y * v.y + v.z * v.z + v.w * v.w;
#pragma unroll
  for (int mk = 1; mk < 64; mk <<= 1) {
    s1 += __shfl_xor(s1, mk);
    s2 += __shfl_xor(s2, mk);
  }
  __shared__ float as1[4], as2[4];
  if ((tid & 63) == 0) { as1[tid >> 6] = s1; as2[tid >> 6] = s2; }
  __syncthreads();
  s1 = as1[0] + as1[1] + as1[2] + as1[3];
  s2 = as2[0] + as2[1] + as2[2] + as2[3];
  float mu = s1 * (1.f / 1024.f);
  float var = s2 * (1.f / 1024.f) - mu * mu;
  float rs = rsqrtf(var + 1e-5f);
  float4 gg = ((const float4*)g)[tid];
  float4 bb = ((const float4*)be)[tid];
  float4 o;
  o.x = (v.x - mu) * rs * gg.x + bb.x;
  o.y = (v.y - mu) * rs * gg.y + bb.y;
  o.z = (v.z - mu) * rs * gg.z + bb.z;
  o.w = (v.w - mu) * rs * gg.w + bb.w;
  ((float4*)p)[tid] = o;
}

extern "C" void kernel_launch(void* const* d_in, const int* in_sizes, int n_in,
                              void* d_out, int out_size, void* d_ws, size_t ws_size,
                              hipStream_t stream) {
  (void)in_sizes; (void)n_in; (void)out_size; (void)ws_size;
  const float* w      = (const float*)d_in[0];
  const float* r_emb  = (const float*)d_in[1];
  const float* r_wb   = (const float*)d_in[2];
  const float* r_bias = (const float*)d_in[3];
  const float* qkv_w  = (const float*)d_in[4];
  const float* o_w    = (const float*)d_in[5];
  const float* ln_g   = (const float*)d_in[6];
  const float* ln_b   = (const float*)d_in[7];
  float* out = (float*)d_out;
  char* ws = (char*)d_ws;

  // workspace layout (bytes); total ~77.7 MB
  u16* w_b    = (u16*)(ws + 0);          // 16 MB; reused as attn_vec after QKV GEMM
  u16* qkvw_t = (u16*)(ws + 16777216);   // 6 MB  [3072][1024]
  u16* ow_t   = (u16*)(ws + 23068672);   // 2 MB  [1024][1024]
  u16* remb_f = (u16*)(ws + 25165824);   // 2 MB  frag order [n][t16][ks][lane][8]
  u16* q_b    = (u16*)(ws + 27262976);   // 16 MB [b][h][i][d]
  u16* k_f    = (u16*)(ws + 44040192);   // 16 MB frag order [bn][j16][ks][lane][8]
  u16* v_f    = (u16*)(ws + 60817408);   // 16 MB frag order [bn][j16][dd][lane][4]
  float* cvb  = (float*)(ws + 77594624); // 64 KB [n][t]
  u16* av_b   = w_b;

  cast_w_k<<<8192, 256, 0, stream>>>(w, w_b);
  transpose_cast_k<<<dim3(96, 32), 256, 0, stream>>>(qkv_w, qkvw_t, 1024, 3072);
  transpose_cast_k<<<dim3(32, 32), 256, 0, stream>>>(o_w, ow_t, 1024, 1024);
  cast_remb_k<<<512, 256, 0, stream>>>(r_emb, remb_f);
  cvec_k<<<64, 256, 0, stream>>>(r_emb, r_wb, cvb);
  gemm_bt<0><<<dim3(24, 64), 256, 0, stream>>>(w_b, qkvw_t, 1024, q_b, k_f, v_f, nullptr, nullptr);
  attn_k<<<dim3(1024), 256, 0, stream>>>(q_b, k_f, v_f, remb_f, r_bias, cvb, r_wb, av_b);
  gemm_bt<1><<<dim3(8, 64), 256, 0, stream>>>(av_b, ow_t, 1024, nullptr, nullptr, nullptr, w, out);
  ln_k<<<8192, 256, 0, stream>>>(out, ln_g, ln_b);
}

// Round 9
// 205.857 us; speedup vs baseline: 2.0252x; 1.0002x over previous
//
#include <hip/hip_runtime.h>

typedef unsigned short u16;
typedef __attribute__((ext_vector_type(8))) short bf16x8;
typedef __attribute__((ext_vector_type(4))) short bf16x4;
typedef __attribute__((ext_vector_type(4))) float f32x4;
typedef __attribute__((ext_vector_type(4))) unsigned short u16x4;

// Problem constants (fixed by the reference)
#define SEQ 1024
#define BSZ 8
#define NHD 16
#define DHD 64
#define DMODEL 1024

__device__ __forceinline__ u16 f2bf(float x) {
  unsigned u = __float_as_uint(x);
  return (u16)((u + 0x7fffu + ((u >> 16) & 1u)) >> 16);  // RNE
}
__device__ __forceinline__ float bf2f(u16 h) {
  return __uint_as_float(((unsigned)h) << 16);
}

typedef const __attribute__((address_space(1))) unsigned int gu32_t;
typedef __attribute__((address_space(3))) unsigned int lu32_t;
__device__ __forceinline__ void gload16(const void* g, void* l) {
  __builtin_amdgcn_global_load_lds((gu32_t*)g, (lu32_t*)l, 16, 0, 0);
}

// ---------------- cast / transpose kernels ----------------
__global__ void cast_w_k(const float* __restrict__ in, u16* __restrict__ out) {
  size_t i = ((size_t)blockIdx.x * 256 + threadIdx.x) * 4;
  float4 v = *(const float4*)(in + i);
  u16x4 o;
  o[0] = f2bf(v.x); o[1] = f2bf(v.y); o[2] = f2bf(v.z); o[3] = f2bf(v.w);
  *(u16x4*)(out + i) = o;
}

// in [R][C] f32 -> out [C][R] bf16
__global__ void transpose_cast_k(const float* __restrict__ in, u16* __restrict__ out,
                                 int R, int C) {
  __shared__ float tile[32][33];
  int tx = threadIdx.x & 31, ty = threadIdx.x >> 5;
  int bx = blockIdx.x * 32, by = blockIdx.y * 32;
#pragma unroll
  for (int rr = ty; rr < 32; rr += 8)
    tile[rr][tx] = in[(size_t)(by + rr) * C + bx + tx];
  __syncthreads();
#pragma unroll
  for (int rr = ty; rr < 32; rr += 8)
    out[(size_t)(bx + rr) * R + by + tx] = f2bf(tile[tx][rr]);
}

// r_emb [j][n][d] f32 -> MFMA-A-fragment order:
// rf[n][t16][ks][lane][8], lane = (t&15) | ((d>>3)&3)<<4, elems d&7
__global__ void cast_remb_k(const float* __restrict__ in, u16* __restrict__ out) {
  int t0 = blockIdx.x * 256 + threadIdx.x;  // (j*16+n)*8 + db
  int jn = t0 >> 3, db = t0 & 7;            // db: which 8-d octet
  int j = jn >> 4, n = jn & 15;
  const float* src = in + (size_t)jn * 64 + db * 8;
  u16* dst = out + (size_t)n * 65536 + (size_t)(j >> 4) * 1024 + (db >> 2) * 512 +
             (((j & 15) | ((db & 3) << 4)) << 3);
#pragma unroll
  for (int e = 0; e < 8; ++e) dst[e] = f2bf(src[e]);
}

// c[n][t] = r_w_bias[n] . r_emb[t][n][:]  (f32, exact)
__global__ void cvec_k(const float* __restrict__ remb, const float* __restrict__ rwb,
                       float* __restrict__ cv) {
  int idx = blockIdx.x * 256 + threadIdx.x;  // n*1024 + t
  int n = idx >> 10, t = idx & 1023;
  const float* src = remb + (size_t)(t * 16 + n) * 64;
  const float* wb = rwb + n * 64;
  float s = 0.f;
#pragma unroll
  for (int d = 0; d < 64; ++d) s += src[d] * wb[d];
  cv[idx] = s;
}

// ---------------- GEMM: C[M,N] = A[M,K] @ Bt[N,K]^T  (bf16, 128x128 tile) ----------------
// 1-D grid with XCD-chunked swizzle (T1): each XCD gets a contiguous bm-major
// run of logical tiles -> its A-row panels (2MB) stay L2-resident, bn streams.
// EPI 0: scatter q normal [b][h][i][d]; K and V in MFMA-fragment order (see attn_k).
// EPI 1: yout = resid + C (f32).
template <int EPI>
__global__ __launch_bounds__(256) void gemm_bt(
    const u16* __restrict__ A, const u16* __restrict__ Bt, int K, int nbn,
    u16* __restrict__ q_o, u16* __restrict__ k_o, u16* __restrict__ v_o,
    const float* __restrict__ resid, float* __restrict__ yout) {
  __shared__ __attribute__((aligned(16))) u16 ldsA[2][4096];  // [128 rows][32 k]
  __shared__ __attribute__((aligned(16))) u16 ldsB[2][4096];
  const int tid = threadIdx.x;
  const int wid = tid >> 6, l = tid & 63;
  const int l15 = l & 15, lg = l >> 4;
  // XCD-chunked bijective remap (gridDim.x % 8 == 0 for both uses)
  const int cpx = gridDim.x >> 3;
  const int id0 = blockIdx.x;
  const int lid = (id0 & 7) * cpx + (id0 >> 3);
  const int bm = lid / nbn, bn = lid % nbn;
  const int wm = wid & 1, wn = wid >> 1;
  const size_t ldb = (size_t)K * 2;  // row bytes

  const char* aA = (const char*)A + (size_t)(bm * 128 + wid * 32 + (l >> 2)) * ldb + (l & 3) * 16;
  const char* aB = (const char*)Bt + (size_t)(bn * 128 + wid * 32 + (l >> 2)) * ldb + (l & 3) * 16;

  auto stage = [&](int buf, int kt) {
    const char* sa = aA + (size_t)kt * 64;
    const char* sb = aB + (size_t)kt * 64;
    char* la = (char*)&ldsA[buf][wid * 1024];
    char* lb = (char*)&ldsB[buf][wid * 1024];
    gload16(sa, la);
    gload16(sa + 16 * ldb, la + 1024);
    gload16(sb, lb);
    gload16(sb + 16 * ldb, lb + 1024);
  };

  f32x4 acc[4][4] = {};
  stage(0, 0);
  __syncthreads();
  const int NT = K >> 5;
  for (int t = 0; t < NT; ++t) {
    int cur = t & 1;
    if (t + 1 < NT) stage(cur ^ 1, t + 1);
    bf16x8 af[4], bfr[4];
#pragma unroll
    for (int mi = 0; mi < 4; ++mi)
      af[mi] = *(const bf16x8*)&ldsA[cur][(wm * 64 + mi * 16 + l15) * 32 + lg * 8];
#pragma unroll
    for (int ni = 0; ni < 4; ++ni)
      bfr[ni] = *(const bf16x8*)&ldsB[cur][(wn * 64 + ni * 16 + l15) * 32 + lg * 8];
#pragma unroll
    for (int mi = 0; mi < 4; ++mi)
#pragma unroll
      for (int ni = 0; ni < 4; ++ni)
        acc[mi][ni] = __builtin_amdgcn_mfma_f32_16x16x32_bf16(af[mi], bfr[ni], acc[mi][ni], 0, 0, 0);
    __syncthreads();
  }

  if (EPI == 0) {
#pragma unroll
    for (int mi = 0; mi < 4; ++mi)
#pragma unroll
      for (int ni = 0; ni < 4; ++ni) {
        int c = bn * 128 + wn * 64 + ni * 16 + l15;
        int which = c >> 10, rem = c & 1023, h = rem >> 6, d = rem & 63;
        u16* dst = which == 0 ? q_o : (which == 1 ? k_o : v_o);
#pragma unroll
        for (int r = 0; r < 4; ++r) {
          int rg = bm * 128 + wm * 64 + mi * 16 + lg * 4 + r;
          int i = rg >> 3, bb = rg & 7;
          int bn2 = bb * 16 + h;
          size_t idx;
          if (which == 0) {
            idx = ((size_t)bn2 * 1024 + i) * 64 + d;
          } else if (which == 1) {
            // K frag: [bn][j16][ks][lane][8]
            idx = (size_t)bn2 * 65536 + (size_t)(i >> 4) * 1024 + (d >> 5) * 512 +
                  (((i & 15) | (((d >> 3) & 3) << 4)) << 3) + (d & 7);
          } else {
            // V frag: [bn][j16][dd][lane][4]
            idx = (size_t)bn2 * 65536 + (size_t)(i >> 4) * 1024 + (d >> 4) * 256 +
                  (((d & 15) | (((i >> 2) & 3) << 4)) << 2) + (i & 3);
          }
          dst[idx] = f2bf(acc[mi][ni][r]);
        }
      }
  } else {
#pragma unroll
    for (int mi = 0; mi < 4; ++mi)
#pragma unroll
      for (int ni = 0; ni < 4; ++ni) {
        int c = bn * 128 + wn * 64 + ni * 16 + l15;
#pragma unroll
        for (int r = 0; r < 4; ++r) {
          int rg = bm * 128 + wm * 64 + mi * 16 + lg * 4 + r;
          size_t off = (size_t)rg * 1024 + c;
          yout[off] = resid[off] + acc[mi][ni][r];
        }
      }
  }
}

// ---------------- fused causal rel-attention (barrier-free, 32 q-rows/wave) ----------
// Block: 128 q-rows (4 waves x 32 rows as 2x16 subgroups A/B), KV tiles of 64.
// Subgroups SHARE the K and V fragments; E windows overlap by 64 -> 6 r_emb
// frags cover both. Only the LAST tile needs masking. Barrier-free loop, each
// wave to its OWN njt. Longest blocks first. Softmax in exp2 domain:
// SC = 0.125*log2(e); p = 2^(SC*(s+E) - m); threshold 11.5 ~= e^8 bound.
__global__ __launch_bounds__(256, 3) void attn_k(
    const u16* __restrict__ qg, const u16* __restrict__ kf, const u16* __restrict__ vf,
    const u16* __restrict__ rf, const float* __restrict__ rbias,
    const float* __restrict__ cvec, const float* __restrict__ rwb,
    u16* __restrict__ av) {
  __shared__ __attribute__((aligned(16))) float EldsA[4][16][84];
  __shared__ __attribute__((aligned(16))) float EldsB[4][16][84];
  __shared__ __attribute__((aligned(16))) float rb[1088];

  const int tid = threadIdx.x;
  const int wid = tid >> 6, l = tid & 63;
  const int l15 = l & 15, lg = l >> 4;
  const int id = blockIdx.x;
  const int qblk = 7 - (id >> 7);    // longest-first dispatch (128 rows/block)
  const int n = (id & 7) | (((id >> 3) & 1) << 3);  // id%8 keys head%8 (XCD grouping)
  const int b = (id >> 4) & 7;
  const int bn = b * 16 + n;
  const int ib = qblk * 128;
  const int iw = ib + wid * 32;      // wave base: subgroup A rows iw.., B rows iw+16..

  const float SC = 0.18033688011f;   // 0.125 * log2(e)

  for (int idx = tid; idx < 1088; idx += 256)
    rb[idx] = (idx < 1024) ? (rbias[idx * 16 + n] - cvec[n * 1024 + idx]) : 0.f;

  // Q fragment sets (r_w_bias folded), one per subgroup
  const float* wbp = rwb + n * 64;
  const u16* qrowA = qg + ((size_t)bn * 1024 + iw + l15) * 64;
  const u16* qrowB = qrowA + 16 * 64;
  bf16x8 qa0 = *(const bf16x8*)(qrowA + lg * 8);
  bf16x8 qa1 = *(const bf16x8*)(qrowA + 32 + lg * 8);
  bf16x8 qb0 = *(const bf16x8*)(qrowB + lg * 8);
  bf16x8 qb1 = *(const bf16x8*)(qrowB + 32 + lg * 8);
  bf16x8 qwA0, qwA1, qwB0, qwB1;
#pragma unroll
  for (int e = 0; e < 8; ++e) {
    float w0 = wbp[lg * 8 + e], w1 = wbp[32 + lg * 8 + e];
    qwA0[e] = (short)f2bf(bf2f((u16)qa0[e]) + w0);
    qwA1[e] = (short)f2bf(bf2f((u16)qa1[e]) + w1);
    qwB0[e] = (short)f2bf(bf2f((u16)qb0[e]) + w0);
    qwB1[e] = (short)f2bf(bf2f((u16)qb1[e]) + w1);
  }

  f32x4 oaccA[4] = {}, oaccB[4] = {};
  float mA = -1e30f, lA = 0.f, mB = -1e30f, lB = 0.f;

  // per-lane fragment pointers (lane-major frag layouts, fully coalesced)
  const u16* kfp = kf + (size_t)bn * 65536 + l * 8;
  const u16* vfp = vf + (size_t)bn * 65536 + l * 4;
  const u16* rfp = rf + (size_t)n * 65536 + l * 8;

  const int dAm = (iw & 63) + l15;   // last-tile mask thresholds
  const int dBm = dAm + 16;

  __syncthreads();  // rb visible (the only barrier)

  const int njt = (iw >> 6) + 1;     // per-wave tile count (barrier-free)
  for (int jt = 0; jt < njt; ++jt) {
    const int jb = jt * 64;

    // ---- K fragments: 8 coalesced 1KB loads (shared by A and B) ----
    const u16* kt = kfp + jt * 4096;
    bf16x8 kk[8];
#pragma unroll
    for (int s = 0; s < 8; ++s) kk[s] = *(const bf16x8*)(kt + s * 512);

    // ---- E phase: 6 frags cover both subgroups' windows ----
    const int tbB = jb - iw - 16 + 1008;  // subgroup B window base (A = tbB+16)
    const int t16b = tbB >> 4;
#pragma unroll
    for (int f = 0; f < 6; ++f) {
      int t16 = t16b + f;
      if (t16 > 63) t16 = 63;  // >1023 rows are masked region anyway
      const u16* rr = rfp + t16 * 1024;
      bf16x8 ra0 = *(const bf16x8*)(rr);
      bf16x8 ra1 = *(const bf16x8*)(rr + 512);
      f32x4 rb4 = *(const f32x4*)&rb[tbB + f * 16 + lg * 4];
      if (f < 5) {
        f32x4 et = {};
        et = __builtin_amdgcn_mfma_f32_16x16x32_bf16(ra0, qwB0, et, 0, 0, 0);
        et = __builtin_amdgcn_mfma_f32_16x16x32_bf16(ra1, qwB1, et, 0, 0, 0);
        *(f32x4*)&EldsB[wid][l15][f * 16 + lg * 4] = et + rb4;
      }
      if (f >= 1) {
        f32x4 et = {};
        et = __builtin_amdgcn_mfma_f32_16x16x32_bf16(ra0, qwA0, et, 0, 0, 0);
        et = __builtin_amdgcn_mfma_f32_16x16x32_bf16(ra1, qwA1, et, 0, 0, 0);
        *(f32x4*)&EldsA[wid][l15][(f - 1) * 16 + lg * 4] = et + rb4;
      }
    }

    // ---- S^T = K.(q+rwb) for both subgroups (K regs shared, then dead) ----
    f32x4 stA[4], stB[4];
    __builtin_amdgcn_s_setprio(1);
#pragma unroll
    for (int jj = 0; jj < 4; ++jj) {
      f32x4 a = __builtin_amdgcn_mfma_f32_16x16x32_bf16(kk[jj * 2], qwA0, (f32x4){}, 0, 0, 0);
      stA[jj] = __builtin_amdgcn_mfma_f32_16x16x32_bf16(kk[jj * 2 + 1], qwA1, a, 0, 0, 0);
    }
#pragma unroll
    for (int jj = 0; jj < 4; ++jj) {
      f32x4 a = __builtin_amdgcn_mfma_f32_16x16x32_bf16(kk[jj * 2], qwB0, (f32x4){}, 0, 0, 0);
      stB[jj] = __builtin_amdgcn_mfma_f32_16x16x32_bf16(kk[jj * 2 + 1], qwB1, a, 0, 0, 0);
    }
    __builtin_amdgcn_s_setprio(0);

    // ---- V fragments: 16 coalesced 512B loads (shared; hide under softmax) ----
    const u16* vt0 = vfp + jt * 4096;
    bf16x4 vv[4][4];
#pragma unroll
    for (int jj = 0; jj < 4; ++jj)
#pragma unroll
      for (int dd = 0; dd < 4; ++dd)
        vv[jj][dd] = *(const bf16x4*)(vt0 + jj * 1024 + dd * 256);

    // ---- softmax in exp2 domain (both subgroups) ----
    const bool domask = (jt == njt - 1);  // both diagonals live in the last tile
    float tmaxA = -1e30f, tmaxB = -1e30f;
#pragma unroll
    for (int jj = 0; jj < 4; ++jj)
#pragma unroll
      for (int r2 = 0; r2 < 4; ++r2) {
        int jl = jj * 16 + lg * 4 + r2;
        float va = stA[jj][r2] + EldsA[wid][l15][jl - l15 + 15];
        float vb = stB[jj][r2] + EldsB[wid][l15][jl - l15 + 15];
        va *= SC; vb *= SC;
        if (domask) {
          if (jl > dAm) va = -1e30f;
          if (jl > dBm) vb = -1e30f;
        }
        stA[jj][r2] = va; stB[jj][r2] = vb;
        tmaxA = fmaxf(tmaxA, va); tmaxB = fmaxf(tmaxB, vb);
      }
    tmaxA = fmaxf(tmaxA, __shfl_xor(tmaxA, 16));
    tmaxA = fmaxf(tmaxA, __shfl_xor(tmaxA, 32));
    tmaxB = fmaxf(tmaxB, __shfl_xor(tmaxB, 16));
    tmaxB = fmaxf(tmaxB, __shfl_xor(tmaxB, 32));

    // defer-max (T13): 11.5 in log2 domain ~= the e^8 bound
    if (!__all(fmaxf(tmaxA - mA, tmaxB - mB) <= 11.5f)) {
      float mnA = fmaxf(mA, tmaxA), mnB = fmaxf(mB, tmaxB);
      float facA = exp2f(mA - mnA), facB = exp2f(mB - mnB);
      mA = mnA; mB = mnB;
      lA *= facA; lB *= facB;
      float foA[4], foB[4];
#pragma unroll
      for (int r2 = 0; r2 < 4; ++r2) {
        foA[r2] = __shfl(facA, (l & 48) | (lg * 4 + r2));
        foB[r2] = __shfl(facB, (l & 48) | (lg * 4 + r2));
      }
#pragma unroll
      for (int dd = 0; dd < 4; ++dd)
#pragma unroll
        for (int r2 = 0; r2 < 4; ++r2) {
          oaccA[dd][r2] *= foA[r2];
          oaccB[dd][r2] *= foB[r2];
        }
    }

    float psA = 0.f, psB = 0.f;
    bf16x4 paA[4], paB[4];
#pragma unroll
    for (int jj = 0; jj < 4; ++jj)
#pragma unroll
      for (int r2 = 0; r2 < 4; ++r2) {
        float pA = exp2f(stA[jj][r2] - mA);
        float pB = exp2f(stB[jj][r2] - mB);
        psA += pA; psB += pB;
        paA[jj][r2] = (short)f2bf(pA);
        paB[jj][r2] = (short)f2bf(pB);
      }
    psA += __shfl_xor(psA, 16);
    psA += __shfl_xor(psA, 32);
    psB += __shfl_xor(psB, 16);
    psB += __shfl_xor(psB, 32);
    lA += psA; lB += psB;

    // ---- PV: P is the 16x16x16 A-fragment; V frags shared by A and B ----
    __builtin_amdgcn_s_setprio(1);
#pragma unroll
    for (int dd = 0; dd < 4; ++dd)
#pragma unroll
      for (int jj = 0; jj < 4; ++jj)
        oaccA[dd] = __builtin_amdgcn_mfma_f32_16x16x16bf16_1k(paA[jj], vv[jj][dd], oaccA[dd], 0, 0, 0);
#pragma unroll
    for (int dd = 0; dd < 4; ++dd)
#pragma unroll
      for (int jj = 0; jj < 4; ++jj)
        oaccB[dd] = __builtin_amdgcn_mfma_f32_16x16x16bf16_1k(paB[jj], vv[jj][dd], oaccB[dd], 0, 0, 0);
    __builtin_amdgcn_s_setprio(0);
  }

  float liA = 1.f / lA, liB = 1.f / lB;
  float ioA[4], ioB[4];
#pragma unroll
  for (int r2 = 0; r2 < 4; ++r2) {
    ioA[r2] = __shfl(liA, (l & 48) | (lg * 4 + r2));
    ioB[r2] = __shfl(liB, (l & 48) | (lg * 4 + r2));
  }
#pragma unroll
  for (int dd = 0; dd < 4; ++dd)
#pragma unroll
    for (int r2 = 0; r2 < 4; ++r2) {
      int igA = iw + lg * 4 + r2;
      av[((size_t)igA * 8 + b) * 1024 + n * 64 + dd * 16 + l15] = f2bf(oaccA[dd][r2] * ioA[r2]);
      int igB = igA + 16;
      av[((size_t)igB * 8 + b) * 1024 + n * 64 + dd * 16 + l15] = f2bf(oaccB[dd][r2] * ioB[r2]);
    }
}

// ---------------- in-place LayerNorm over rows of 1024 ----------------
__global__ void ln_k(float* __restrict__ y, const float* __restrict__ g,
                     const float* __restrict__ be) {
  const int row = blockIdx.x, tid = threadIdx.x;
  float* p = y + (size_t)row * 1024;
  float4 v = ((const float4*)p)[tid];
  float s1 = v.x + v.y + v.z + v.w;
  float s2 = v.x * v.x + v.y * v.y + v.z * v.z + v.w * v.w;
#pragma unroll
  for (int mk = 1; mk < 64; mk <<= 1) {
    s1 += __shfl_xor(s1, mk);
    s2 += __shfl_xor(s2, mk);
  }
  __shared__ float as1[4], as2[4];
  if ((tid & 63) == 0) { as1[tid >> 6] = s1; as2[tid >> 6] = s2; }
  __syncthreads();
  s1 = as1[0] + as1[1] + as1[2] + as1[3];
  s2 = as2[0] + as2[1] + as2[2] + as2[3];
  float mu = s1 * (1.f / 1024.f);
  float var = s2 * (1.f / 1024.f) - mu * mu;
  float rs = rsqrtf(var + 1e-5f);
  float4 gg = ((const float4*)g)[tid];
  float4 bb = ((const float4*)be)[tid];
  float4 o;
  o.x = (v.x - mu) * rs * gg.x + bb.x;
  o.y = (v.y - mu) * rs * gg.y + bb.y;
  o.z = (v.z - mu) * rs * gg.z + bb.z;
  o.w = (v.w - mu) * rs * gg.w + bb.w;
  ((float4*)p)[tid] = o;
}

extern "C" void kernel_launch(void* const* d_in, const int* in_sizes, int n_in,
                              void* d_out, int out_size, void* d_ws, size_t ws_size,
                              hipStream_t stream) {
  (void)in_sizes; (void)n_in; (void)out_size; (void)ws_size;
  const float* w      = (const float*)d_in[0];
  const float* r_emb  = (const float*)d_in[1];
  const float* r_wb   = (const float*)d_in[2];
  const float* r_bias = (const float*)d_in[3];
  const float* qkv_w  = (const float*)d_in[4];
  const float* o_w    = (const float*)d_in[5];
  const float* ln_g   = (const float*)d_in[6];
  const float* ln_b   = (const float*)d_in[7];
  float* out = (float*)d_out;
  char* ws = (char*)d_ws;

  // workspace layout (bytes); total ~77.7 MB
  u16* w_b    = (u16*)(ws + 0);          // 16 MB; reused as attn_vec after QKV GEMM
  u16* qkvw_t = (u16*)(ws + 16777216);   // 6 MB  [3072][1024]
  u16* ow_t   = (u16*)(ws + 23068672);   // 2 MB  [1024][1024]
  u16* remb_f = (u16*)(ws + 25165824);   // 2 MB  frag order [n][t16][ks][lane][8]
  u16* q_b    = (u16*)(ws + 27262976);   // 16 MB [b][h][i][d]
  u16* k_f    = (u16*)(ws + 44040192);   // 16 MB frag order [bn][j16][ks][lane][8]
  u16* v_f    = (u16*)(ws + 60817408);   // 16 MB frag order [bn][j16][dd][lane][4]
  float* cvb  = (float*)(ws + 77594624); // 64 KB [n][t]
  u16* av_b   = w_b;

  cast_w_k<<<8192, 256, 0, stream>>>(w, w_b);
  transpose_cast_k<<<dim3(96, 32), 256, 0, stream>>>(qkv_w, qkvw_t, 1024, 3072);
  transpose_cast_k<<<dim3(32, 32), 256, 0, stream>>>(o_w, ow_t, 1024, 1024);
  cast_remb_k<<<512, 256, 0, stream>>>(r_emb, remb_f);
  cvec_k<<<64, 256, 0, stream>>>(r_emb, r_wb, cvb);
  gemm_bt<0><<<dim3(1536), 256, 0, stream>>>(w_b, qkvw_t, 1024, 24, q_b, k_f, v_f, nullptr, nullptr);
  attn_k<<<dim3(1024), 256, 0, stream>>>(q_b, k_f, v_f, remb_f, r_bias, cvb, r_wb, av_b);
  gemm_bt<1><<<dim3(512), 256, 0, stream>>>(av_b, ow_t, 1024, 8, nullptr, nullptr, nullptr, w, out);
  ln_k<<<8192, 256, 0, stream>>>(out, ln_g, ln_b);
}

// Round 10
// 199.367 us; speedup vs baseline: 2.0911x; 1.0326x over previous
//
#include <hip/hip_runtime.h>

typedef unsigned short u16;
typedef __attribute__((ext_vector_type(8))) short bf16x8;
typedef __attribute__((ext_vector_type(4))) short bf16x4;
typedef __attribute__((ext_vector_type(4))) float f32x4;
typedef __attribute__((ext_vector_type(4))) unsigned short u16x4;
typedef __attribute__((ext_vector_type(2))) unsigned int u32x2;

// Problem constants (fixed by the reference)
#define SEQ 1024
#define BSZ 8
#define NHD 16
#define DHD 64
#define DMODEL 1024

__device__ __forceinline__ u16 f2bf(float x) {
  unsigned u = __float_as_uint(x);
  return (u16)((u + 0x7fffu + ((u >> 16) & 1u)) >> 16);  // RNE
}
__device__ __forceinline__ float bf2f(u16 h) {
  return __uint_as_float(((unsigned)h) << 16);
}

typedef const __attribute__((address_space(1))) unsigned int gu32_t;
typedef __attribute__((address_space(3))) unsigned int lu32_t;
__device__ __forceinline__ void gload16(const void* g, void* l) {
  __builtin_amdgcn_global_load_lds((gu32_t*)g, (lu32_t*)l, 16, 0, 0);
}

// ---------------- cast / transpose kernels ----------------
__global__ void cast_w_k(const float* __restrict__ in, u16* __restrict__ out) {
  size_t i = ((size_t)blockIdx.x * 256 + threadIdx.x) * 4;
  float4 v = *(const float4*)(in + i);
  u16x4 o;
  o[0] = f2bf(v.x); o[1] = f2bf(v.y); o[2] = f2bf(v.z); o[3] = f2bf(v.w);
  *(u16x4*)(out + i) = o;
}

// in [R][C] f32 -> out [C][R] bf16
__global__ void transpose_cast_k(const float* __restrict__ in, u16* __restrict__ out,
                                 int R, int C) {
  __shared__ float tile[32][33];
  int tx = threadIdx.x & 31, ty = threadIdx.x >> 5;
  int bx = blockIdx.x * 32, by = blockIdx.y * 32;
#pragma unroll
  for (int rr = ty; rr < 32; rr += 8)
    tile[rr][tx] = in[(size_t)(by + rr) * C + bx + tx];
  __syncthreads();
#pragma unroll
  for (int rr = ty; rr < 32; rr += 8)
    out[(size_t)(bx + rr) * R + by + tx] = f2bf(tile[tx][rr]);
}

// r_emb [j][n][d] f32 -> MFMA-A-fragment order:
// rf[n][t16][ks][lane][8], lane = (t&15) | ((d>>3)&3)<<4, elems d&7
__global__ void cast_remb_k(const float* __restrict__ in, u16* __restrict__ out) {
  int t0 = blockIdx.x * 256 + threadIdx.x;  // (j*16+n)*8 + db
  int jn = t0 >> 3, db = t0 & 7;            // db: which 8-d octet
  int j = jn >> 4, n = jn & 15;
  const float* src = in + (size_t)jn * 64 + db * 8;
  u16* dst = out + (size_t)n * 65536 + (size_t)(j >> 4) * 1024 + (db >> 2) * 512 +
             (((j & 15) | ((db & 3) << 4)) << 3);
#pragma unroll
  for (int e = 0; e < 8; ++e) dst[e] = f2bf(src[e]);
}

// c[n][t] = r_w_bias[n] . r_emb[t][n][:]  (f32, exact)
__global__ void cvec_k(const float* __restrict__ remb, const float* __restrict__ rwb,
                       float* __restrict__ cv) {
  int idx = blockIdx.x * 256 + threadIdx.x;  // n*1024 + t
  int n = idx >> 10, t = idx & 1023;
  const float* src = remb + (size_t)(t * 16 + n) * 64;
  const float* wb = rwb + n * 64;
  float s = 0.f;
#pragma unroll
  for (int d = 0; d < 64; ++d) s += src[d] * wb[d];
  cv[idx] = s;
}

// ---------------- GEMM: C[M,N] = A[M,K] @ Bt[N,K]^T  (bf16, 128x128 tile) ----------------
// 1-D grid with XCD-chunked swizzle (T1): each XCD gets a contiguous bm-major
// run of logical tiles -> its A-row panels (2MB) stay L2-resident, bn streams.
// EPI 0: scatter q normal [b][h][i][d]; K and V in MFMA-fragment order (see attn_k).
// EPI 1: yout = resid + C (f32).
template <int EPI>
__global__ __launch_bounds__(256) void gemm_bt(
    const u16* __restrict__ A, const u16* __restrict__ Bt, int K, int nbn,
    u16* __restrict__ q_o, u16* __restrict__ k_o, u16* __restrict__ v_o,
    const float* __restrict__ resid, float* __restrict__ yout) {
  __shared__ __attribute__((aligned(16))) u16 ldsA[2][4096];  // [128 rows][32 k]
  __shared__ __attribute__((aligned(16))) u16 ldsB[2][4096];
  const int tid = threadIdx.x;
  const int wid = tid >> 6, l = tid & 63;
  const int l15 = l & 15, lg = l >> 4;
  // XCD-chunked bijective remap (gridDim.x % 8 == 0 for both uses)
  const int cpx = gridDim.x >> 3;
  const int id0 = blockIdx.x;
  const int lid = (id0 & 7) * cpx + (id0 >> 3);
  const int bm = lid / nbn, bn = lid % nbn;
  const int wm = wid & 1, wn = wid >> 1;
  const size_t ldb = (size_t)K * 2;  // row bytes

  const char* aA = (const char*)A + (size_t)(bm * 128 + wid * 32 + (l >> 2)) * ldb + (l & 3) * 16;
  const char* aB = (const char*)Bt + (size_t)(bn * 128 + wid * 32 + (l >> 2)) * ldb + (l & 3) * 16;

  auto stage = [&](int buf, int kt) {
    const char* sa = aA + (size_t)kt * 64;
    const char* sb = aB + (size_t)kt * 64;
    char* la = (char*)&ldsA[buf][wid * 1024];
    char* lb = (char*)&ldsB[buf][wid * 1024];
    gload16(sa, la);
    gload16(sa + 16 * ldb, la + 1024);
    gload16(sb, lb);
    gload16(sb + 16 * ldb, lb + 1024);
  };

  f32x4 acc[4][4] = {};
  stage(0, 0);
  __syncthreads();
  const int NT = K >> 5;
  for (int t = 0; t < NT; ++t) {
    int cur = t & 1;
    if (t + 1 < NT) stage(cur ^ 1, t + 1);
    bf16x8 af[4], bfr[4];
#pragma unroll
    for (int mi = 0; mi < 4; ++mi)
      af[mi] = *(const bf16x8*)&ldsA[cur][(wm * 64 + mi * 16 + l15) * 32 + lg * 8];
#pragma unroll
    for (int ni = 0; ni < 4; ++ni)
      bfr[ni] = *(const bf16x8*)&ldsB[cur][(wn * 64 + ni * 16 + l15) * 32 + lg * 8];
#pragma unroll
    for (int mi = 0; mi < 4; ++mi)
#pragma unroll
      for (int ni = 0; ni < 4; ++ni)
        acc[mi][ni] = __builtin_amdgcn_mfma_f32_16x16x32_bf16(af[mi], bfr[ni], acc[mi][ni], 0, 0, 0);
    __syncthreads();
  }

  if (EPI == 0) {
#pragma unroll
    for (int mi = 0; mi < 4; ++mi)
#pragma unroll
      for (int ni = 0; ni < 4; ++ni) {
        int c = bn * 128 + wn * 64 + ni * 16 + l15;
        int which = c >> 10, rem = c & 1023, h = rem >> 6, d = rem & 63;
        u16* dst = which == 0 ? q_o : (which == 1 ? k_o : v_o);
#pragma unroll
        for (int r = 0; r < 4; ++r) {
          int rg = bm * 128 + wm * 64 + mi * 16 + lg * 4 + r;
          int i = rg >> 3, bb = rg & 7;
          int bn2 = bb * 16 + h;
          size_t idx;
          if (which == 0) {
            idx = ((size_t)bn2 * 1024 + i) * 64 + d;
          } else if (which == 1) {
            // K frag: [bn][j16][ks][lane][8]
            idx = (size_t)bn2 * 65536 + (size_t)(i >> 4) * 1024 + (d >> 5) * 512 +
                  (((i & 15) | (((d >> 3) & 3) << 4)) << 3) + (d & 7);
          } else {
            // V frag: [bn][j16][dd][lane][4]
            idx = (size_t)bn2 * 65536 + (size_t)(i >> 4) * 1024 + (d >> 4) * 256 +
                  (((d & 15) | (((i >> 2) & 3) << 4)) << 2) + (i & 3);
          }
          dst[idx] = f2bf(acc[mi][ni][r]);
        }
      }
  } else {
#pragma unroll
    for (int mi = 0; mi < 4; ++mi)
#pragma unroll
      for (int ni = 0; ni < 4; ++ni) {
        int c = bn * 128 + wn * 64 + ni * 16 + l15;
#pragma unroll
        for (int r = 0; r < 4; ++r) {
          int rg = bm * 128 + wm * 64 + mi * 16 + lg * 4 + r;
          size_t off = (size_t)rg * 1024 + c;
          yout[off] = resid[off] + acc[mi][ni][r];
        }
      }
  }
}

// ---------------- fused causal rel-attention (barrier-free, 32 q-rows/wave) ----------
// Block: 128 q-rows (4 waves x 32 rows as 2x16 subgroups A/B), KV tiles of 64.
// Subgroups SHARE the K and V fragments; E windows overlap by 64 -> 6 r_emb
// frags cover both. Barrier-free loop, each wave to its OWN njt.
// Fixed-offset softmax (no running max): scores are bounded, so
//   p = 2^( SC*(AC+B+D) - 16 )   (offset is exact power-of-2, divides out).
// SC folded into qw; rb = SC*(rbias - cvec) - 16; rb PAD = -1e30 implements the
// causal mask through the E path (t>=1024 <=> j>i) -> zero mask instructions.
// P converts via v_cvt_pk_bf16_f32 pairs; exp via raw v_exp_f32 (2^x).
// Elds is bf16 (cvt_pk-packed b64 stores): LDS 25.9 KB -> up to 6 blocks/CU.
__global__ __launch_bounds__(256, 3) void attn_k(
    const u16* __restrict__ qg, const u16* __restrict__ kf, const u16* __restrict__ vf,
    const u16* __restrict__ rf, const float* __restrict__ rbias,
    const float* __restrict__ cvec, const float* __restrict__ rwb,
    u16* __restrict__ av) {
  __shared__ __attribute__((aligned(16))) u16 EldsA[4][16][84];
  __shared__ __attribute__((aligned(16))) u16 EldsB[4][16][84];
  __shared__ __attribute__((aligned(16))) float rb[1088];

  const int tid = threadIdx.x;
  const int wid = tid >> 6, l = tid & 63;
  const int l15 = l & 15, lg = l >> 4;
  const int id = blockIdx.x;
  const int qblk = 7 - (id >> 7);    // longest-first dispatch (128 rows/block)
  const int n = (id & 7) | (((id >> 3) & 1) << 3);  // id%8 keys head%8 (XCD grouping)
  const int b = (id >> 4) & 7;
  const int bn = b * 16 + n;
  const int ib = qblk * 128;
  const int iw = ib + wid * 32;      // wave base: subgroup A rows iw.., B rows iw+16..

  const float SC = 0.18033688011f;   // 0.125 * log2(e)

  // rb = SC*(rbias - cvec) - 16 ; pad (t>=1024 <=> causal-masked) = -1e30
  for (int idx = tid; idx < 1088; idx += 256)
    rb[idx] = (idx < 1024) ? (SC * (rbias[idx * 16 + n] - cvec[n * 1024 + idx]) - 16.0f)
                           : -1e30f;

  // Q fragment sets (r_w_bias folded, SC pre-scaled), one per subgroup
  const float* wbp = rwb + n * 64;
  const u16* qrowA = qg + ((size_t)bn * 1024 + iw + l15) * 64;
  const u16* qrowB = qrowA + 16 * 64;
  bf16x8 qa0 = *(const bf16x8*)(qrowA + lg * 8);
  bf16x8 qa1 = *(const bf16x8*)(qrowA + 32 + lg * 8);
  bf16x8 qb0 = *(const bf16x8*)(qrowB + lg * 8);
  bf16x8 qb1 = *(const bf16x8*)(qrowB + 32 + lg * 8);
  bf16x8 qwA0, qwA1, qwB0, qwB1;
#pragma unroll
  for (int e = 0; e < 8; ++e) {
    float w0 = wbp[lg * 8 + e], w1 = wbp[32 + lg * 8 + e];
    qwA0[e] = (short)f2bf(SC * (bf2f((u16)qa0[e]) + w0));
    qwA1[e] = (short)f2bf(SC * (bf2f((u16)qa1[e]) + w1));
    qwB0[e] = (short)f2bf(SC * (bf2f((u16)qb0[e]) + w0));
    qwB1[e] = (short)f2bf(SC * (bf2f((u16)qb1[e]) + w1));
  }

  f32x4 oaccA[4] = {}, oaccB[4] = {};
  float lpA = 0.f, lpB = 0.f;        // per-lane l partials, reduced once at end

  // per-lane fragment pointers (lane-major frag layouts, fully coalesced)
  const u16* kfp = kf + (size_t)bn * 65536 + l * 8;
  const u16* vfp = vf + (size_t)bn * 65536 + l * 4;
  const u16* rfp = rf + (size_t)n * 65536 + l * 8;

  __syncthreads();  // rb visible (the only barrier)

  const int njt = (iw >> 6) + 1;     // per-wave tile count (barrier-free)
  for (int jt = 0; jt < njt; ++jt) {
    const int jb = jt * 64;

    // ---- K fragments: 8 coalesced 1KB loads (shared by A and B) ----
    const u16* kt = kfp + jt * 4096;
    bf16x8 kk[8];
#pragma unroll
    for (int s = 0; s < 8; ++s) kk[s] = *(const bf16x8*)(kt + s * 512);

    // ---- E phase: 6 frags cover both subgroups' windows; bf16 packed stores ----
    const int tbB = jb - iw - 16 + 1008;  // subgroup B window base (A = tbB+16)
    const int t16b = tbB >> 4;
#pragma unroll
    for (int f = 0; f < 6; ++f) {
      int t16 = t16b + f;
      if (t16 > 63) t16 = 63;  // >1023 rows are masked (rb pad = -1e30) anyway
      const u16* rr = rfp + t16 * 1024;
      bf16x8 ra0 = *(const bf16x8*)(rr);
      bf16x8 ra1 = *(const bf16x8*)(rr + 512);
      f32x4 rb4 = *(const f32x4*)&rb[tbB + f * 16 + lg * 4];
      if (f < 5) {
        f32x4 et = {};
        et = __builtin_amdgcn_mfma_f32_16x16x32_bf16(ra0, qwB0, et, 0, 0, 0);
        et = __builtin_amdgcn_mfma_f32_16x16x32_bf16(ra1, qwB1, et, 0, 0, 0);
        et = et + rb4;
        unsigned lo, hi;
        asm("v_cvt_pk_bf16_f32 %0, %1, %2" : "=v"(lo) : "v"(et[0]), "v"(et[1]));
        asm("v_cvt_pk_bf16_f32 %0, %1, %2" : "=v"(hi) : "v"(et[2]), "v"(et[3]));
        u32x2 t2; t2[0] = lo; t2[1] = hi;
        *(u32x2*)&EldsB[wid][l15][f * 16 + lg * 4] = t2;
      }
      if (f >= 1) {
        f32x4 et = {};
        et = __builtin_amdgcn_mfma_f32_16x16x32_bf16(ra0, qwA0, et, 0, 0, 0);
        et = __builtin_amdgcn_mfma_f32_16x16x32_bf16(ra1, qwA1, et, 0, 0, 0);
        et = et + rb4;
        unsigned lo, hi;
        asm("v_cvt_pk_bf16_f32 %0, %1, %2" : "=v"(lo) : "v"(et[0]), "v"(et[1]));
        asm("v_cvt_pk_bf16_f32 %0, %1, %2" : "=v"(hi) : "v"(et[2]), "v"(et[3]));
        u32x2 t2; t2[0] = lo; t2[1] = hi;
        *(u32x2*)&EldsA[wid][l15][(f - 1) * 16 + lg * 4] = t2;
      }
    }

    // ---- S^T = K.qw for both subgroups (K regs shared, then dead) ----
    f32x4 stA[4], stB[4];
    __builtin_amdgcn_s_setprio(1);
#pragma unroll
    for (int jj = 0; jj < 4; ++jj) {
      f32x4 a = __builtin_amdgcn_mfma_f32_16x16x32_bf16(kk[jj * 2], qwA0, (f32x4){}, 0, 0, 0);
      stA[jj] = __builtin_amdgcn_mfma_f32_16x16x32_bf16(kk[jj * 2 + 1], qwA1, a, 0, 0, 0);
    }
#pragma unroll
    for (int jj = 0; jj < 4; ++jj) {
      f32x4 a = __builtin_amdgcn_mfma_f32_16x16x32_bf16(kk[jj * 2], qwB0, (f32x4){}, 0, 0, 0);
      stB[jj] = __builtin_amdgcn_mfma_f32_16x16x32_bf16(kk[jj * 2 + 1], qwB1, a, 0, 0, 0);
    }
    __builtin_amdgcn_s_setprio(0);

    // ---- V fragments: 16 coalesced 512B loads (shared; hide under softmax) ----
    const u16* vt0 = vfp + jt * 4096;
    bf16x4 vv[4][4];
#pragma unroll
    for (int jj = 0; jj < 4; ++jj)
#pragma unroll
      for (int dd = 0; dd < 4; ++dd)
        vv[jj][dd] = *(const bf16x4*)(vt0 + jj * 1024 + dd * 256);

    // ---- softmax: p = 2^(st + E); mask & offset pre-folded; no reductions ----
    bf16x4 paA[4], paB[4];
#pragma unroll
    for (int jj = 0; jj < 4; ++jj) {
      const int ebase = jj * 16 + lg * 4 - l15 + 15;
      {
        float v0 = stA[jj][0] + bf2f(EldsA[wid][l15][ebase + 0]);
        float v1 = stA[jj][1] + bf2f(EldsA[wid][l15][ebase + 1]);
        float v2 = stA[jj][2] + bf2f(EldsA[wid][l15][ebase + 2]);
        float v3 = stA[jj][3] + bf2f(EldsA[wid][l15][ebase + 3]);
        float p0, p1, p2, p3;
        asm("v_exp_f32 %0, %1" : "=v"(p0) : "v"(v0));
        asm("v_exp_f32 %0, %1" : "=v"(p1) : "v"(v1));
        asm("v_exp_f32 %0, %1" : "=v"(p2) : "v"(v2));
        asm("v_exp_f32 %0, %1" : "=v"(p3) : "v"(v3));
        lpA += (p0 + p1) + (p2 + p3);
        unsigned lo, hi;
        asm("v_cvt_pk_bf16_f32 %0, %1, %2" : "=v"(lo) : "v"(p0), "v"(p1));
        asm("v_cvt_pk_bf16_f32 %0, %1, %2" : "=v"(hi) : "v"(p2), "v"(p3));
        u32x2 t2; t2[0] = lo; t2[1] = hi;
        paA[jj] = __builtin_bit_cast(bf16x4, t2);
      }
      {
        float v0 = stB[jj][0] + bf2f(EldsB[wid][l15][ebase + 0]);
        float v1 = stB[jj][1] + bf2f(EldsB[wid][l15][ebase + 1]);
        float v2 = stB[jj][2] + bf2f(EldsB[wid][l15][ebase + 2]);
        float v3 = stB[jj][3] + bf2f(EldsB[wid][l15][ebase + 3]);
        float p0, p1, p2, p3;
        asm("v_exp_f32 %0, %1" : "=v"(p0) : "v"(v0));
        asm("v_exp_f32 %0, %1" : "=v"(p1) : "v"(v1));
        asm("v_exp_f32 %0, %1" : "=v"(p2) : "v"(v2));
        asm("v_exp_f32 %0, %1" : "=v"(p3) : "v"(v3));
        lpB += (p0 + p1) + (p2 + p3);
        unsigned lo, hi;
        asm("v_cvt_pk_bf16_f32 %0, %1, %2" : "=v"(lo) : "v"(p0), "v"(p1));
        asm("v_cvt_pk_bf16_f32 %0, %1, %2" : "=v"(hi) : "v"(p2), "v"(p3));
        u32x2 t2; t2[0] = lo; t2[1] = hi;
        paB[jj] = __builtin_bit_cast(bf16x4, t2);
      }
    }

    // ---- PV: P is the 16x16x16 A-fragment; V frags shared by A and B ----
    __builtin_amdgcn_s_setprio(1);
#pragma unroll
    for (int dd = 0; dd < 4; ++dd)
#pragma unroll
      for (int jj = 0; jj < 4; ++jj)
        oaccA[dd] = __builtin_amdgcn_mfma_f32_16x16x16bf16_1k(paA[jj], vv[jj][dd], oaccA[dd], 0, 0, 0);
#pragma unroll
    for (int dd = 0; dd < 4; ++dd)
#pragma unroll
      for (int jj = 0; jj < 4; ++jj)
        oaccB[dd] = __builtin_amdgcn_mfma_f32_16x16x16bf16_1k(paB[jj], vv[jj][dd], oaccB[dd], 0, 0, 0);
    __builtin_amdgcn_s_setprio(0);
  }

  // single end-of-kernel l reduction (rows live in the l15 dimension)
  lpA += __shfl_xor(lpA, 16);
  lpA += __shfl_xor(lpA, 32);
  lpB += __shfl_xor(lpB, 16);
  lpB += __shfl_xor(lpB, 32);
  float liA = 1.f / lpA, liB = 1.f / lpB;
  float ioA[4], ioB[4];
#pragma unroll
  for (int r2 = 0; r2 < 4; ++r2) {
    ioA[r2] = __shfl(liA, (l & 48) | (lg * 4 + r2));
    ioB[r2] = __shfl(liB, (l & 48) | (lg * 4 + r2));
  }
#pragma unroll
  for (int dd = 0; dd < 4; ++dd)
#pragma unroll
    for (int r2 = 0; r2 < 4; ++r2) {
      int igA = iw + lg * 4 + r2;
      av[((size_t)igA * 8 + b) * 1024 + n * 64 + dd * 16 + l15] = f2bf(oaccA[dd][r2] * ioA[r2]);
      int igB = igA + 16;
      av[((size_t)igB * 8 + b) * 1024 + n * 64 + dd * 16 + l15] = f2bf(oaccB[dd][r2] * ioB[r2]);
    }
}

// ---------------- in-place LayerNorm over rows of 1024 ----------------
__global__ void ln_k(float* __restrict__ y, const float* __restrict__ g,
                     const float* __restrict__ be) {
  const int row = blockIdx.x, tid = threadIdx.x;
  float* p = y + (size_t)row * 1024;
  float4 v = ((const float4*)p)[tid];
  float s1 = v.x + v.y + v.z + v.w;
  float s2 = v.x * v.x + v.y * v.y + v.z * v.z + v.w * v.w;
#pragma unroll
  for (int mk = 1; mk < 64; mk <<= 1) {
    s1 += __shfl_xor(s1, mk);
    s2 += __shfl_xor(s2, mk);
  }
  __shared__ float as1[4], as2[4];
  if ((tid & 63) == 0) { as1[tid >> 6] = s1; as2[tid >> 6] = s2; }
  __syncthreads();
  s1 = as1[0] + as1[1] + as1[2] + as1[3];
  s2 = as2[0] + as2[1] + as2[2] + as2[3];
  float mu = s1 * (1.f / 1024.f);
  float var = s2 * (1.f / 1024.f) - mu * mu;
  float rs = rsqrtf(var + 1e-5f);
  float4 gg = ((const float4*)g)[tid];
  float4 bb = ((const float4*)be)[tid];
  float4 o;
  o.x = (v.x - mu) * rs * gg.x + bb.x;
  o.y = (v.y - mu) * rs * gg.y + bb.y;
  o.z = (v.z - mu) * rs * gg.z + bb.z;
  o.w = (v.w - mu) * rs * gg.w + bb.w;
  ((float4*)p)[tid] = o;
}

extern "C" void kernel_launch(void* const* d_in, const int* in_sizes, int n_in,
                              void* d_out, int out_size, void* d_ws, size_t ws_size,
                              hipStream_t stream) {
  (void)in_sizes; (void)n_in; (void)out_size; (void)ws_size;
  const float* w      = (const float*)d_in[0];
  const float* r_emb  = (const float*)d_in[1];
  const float* r_wb   = (const float*)d_in[2];
  const float* r_bias = (const float*)d_in[3];
  const float* qkv_w  = (const float*)d_in[4];
  const float* o_w    = (const float*)d_in[5];
  const float* ln_g   = (const float*)d_in[6];
  const float* ln_b   = (const float*)d_in[7];
  float* out = (float*)d_out;
  char* ws = (char*)d_ws;

  // workspace layout (bytes); total ~77.7 MB
  u16* w_b    = (u16*)(ws + 0);          // 16 MB; reused as attn_vec after QKV GEMM
  u16* qkvw_t = (u16*)(ws + 16777216);   // 6 MB  [3072][1024]
  u16* ow_t   = (u16*)(ws + 23068672);   // 2 MB  [1024][1024]
  u16* remb_f = (u16*)(ws + 25165824);   // 2 MB  frag order [n][t16][ks][lane][8]
  u16* q_b    = (u16*)(ws + 27262976);   // 16 MB [b][h][i][d]
  u16* k_f    = (u16*)(ws + 44040192);   // 16 MB frag order [bn][j16][ks][lane][8]
  u16* v_f    = (u16*)(ws + 60817408);   // 16 MB frag order [bn][j16][dd][lane][4]
  float* cvb  = (float*)(ws + 77594624); // 64 KB [n][t]
  u16* av_b   = w_b;

  cast_w_k<<<8192, 256, 0, stream>>>(w, w_b);
  transpose_cast_k<<<dim3(96, 32), 256, 0, stream>>>(qkv_w, qkvw_t, 1024, 3072);
  transpose_cast_k<<<dim3(32, 32), 256, 0, stream>>>(o_w, ow_t, 1024, 1024);
  cast_remb_k<<<512, 256, 0, stream>>>(r_emb, remb_f);
  cvec_k<<<64, 256, 0, stream>>>(r_emb, r_wb, cvb);
  gemm_bt<0><<<dim3(1536), 256, 0, stream>>>(w_b, qkvw_t, 1024, 24, q_b, k_f, v_f, nullptr, nullptr);
  attn_k<<<dim3(1024), 256, 0, stream>>>(q_b, k_f, v_f, remb_f, r_bias, cvb, r_wb, av_b);
  gemm_bt<1><<<dim3(512), 256, 0, stream>>>(av_b, ow_t, 1024, 8, nullptr, nullptr, nullptr, w, out);
  ln_k<<<8192, 256, 0, stream>>>(out, ln_g, ln_b);
}